// Round 7
// baseline (1030.269 us; speedup 1.0000x reference)
//
#include <hip/hip_runtime.h>
#include <math.h>

#define N_TOK 8192
#define DIM   1024
#define HID   2048
#define NE    8
#define NPAIR (N_TOK * 2)          // 16384 (token, expert) pairs exactly
#define CAPP  (NPAIR + NE * 128)   // 17408: expert regions padded to 128 rows
#define TAIL  (N_TOK * DIM)        // offset of scalar outputs in d_out

typedef __bf16 bf16x8_t __attribute__((ext_vector_type(8)));
typedef float  f32x4_t  __attribute__((ext_vector_type(4)));

__device__ __forceinline__ unsigned short f2bf(float f) {
  union { float f; unsigned u; } v; v.f = f;
  unsigned r = v.u + 0x7fffu + ((v.u >> 16) & 1u);   // RNE
  return (unsigned short)(r >> 16);
}

__device__ __forceinline__ float bf2f(unsigned short h) {
  union { unsigned u; float f; } v; v.u = ((unsigned)h) << 16;
  return v.f;
}

__device__ __forceinline__ float gelu_exact(float v) {
  return 0.5f * v * (1.f + erff(v * 0.70710678118654752440f));
}

// async global->LDS DMA, 16B/lane; LDS base wave-uniform, HW scatters lane*16.
__device__ __forceinline__ void load16_lds(const void* g, void* l) {
  __builtin_amdgcn_global_load_lds(
      (const __attribute__((address_space(1))) unsigned int*)g,
      (__attribute__((address_space(3))) unsigned int*)l, 16, 0, 0);
}

// =======================================================================
// Fragment-chunk global layout (R4): a matrix [R rows][Kd k] is stored as
// 1KB chunks; chunk c = (r>>4)*(Kd/32) + (k>>5); within a chunk, lane
// l = (k>>3&3)*16 + (r&15) owns 16B = 8 shorts (k&7 fastest). A GEMM tile
// stage is ONE contiguous-1KB global_load_lds per chunk and fragment
// ds_read_b128 is sequential (0 bank conflicts, proven R3).
//
// R10 post-mortem: unified VGPR+AGPR pool = 512/SIMD (m69). The inner
// loop needs 128 regs/wave -> 4 waves/SIMD is the HARD cap; asking for 5
// spilled acc to scratch (VGPR 48, WRITE 824MB). 4 blocks/CU is final.
//
// R11: fuse gemm1+gemm2 into ONE persistent kernel to overlap gemm1's
// quantization tail with gemm2's start (occupancy can't rise, so fill
// the bubble with dependent work instead). Global unit list interleaved
// per rt: [16 gemm1 units][8 gemm2 tiles x 2 units]; contiguous weighted
// ranges over 1024 XCD-swizzled blocks (He produced & consumed on the
// same XCD -> L2 hits). Per-rt ready counters: g1 tile completion does
// vmcnt(0)+barrier+threadfence+atomicAdd(rdy[rt]); g2 tiles spin until
// rdy[rt]==16 (tid0, s_sleep, bounded valve), then acquire-fence.
// Deadlock-free: deps point to strictly earlier units (acyclic) and
// launch_bounds(256,4) + exactly-32KB LDS guarantees all 1024 blocks
// co-resident (4/CU, proven in R9). yb aliases Ab1: same rdy[rt]==16
// gate protects it (per-rt byte ranges identical & exclusive).
// =======================================================================

// ---------------- weights fp32 [z][Kd][R] -> frag-chunk bf16 ----------------
template<int KD, int RR>
__global__ __launch_bounds__(256) void w_to_frag(const float* __restrict__ src,
                                                 unsigned short* __restrict__ dst) {
  constexpr int KD32 = KD / 32;
  int z = blockIdx.z;
  int cl = blockIdx.x * 4 + (threadIdx.x >> 6);   // chunk id (grid sized exactly)
  int lane = threadIdx.x & 63, m16 = lane & 15, q = lane >> 4;
  int rblk = cl / KD32, kblk = cl % KD32;         // pow2 -> shifts
  int r = rblk * 16 + m16;
  int kb = kblk * 32 + q * 8;
  const float* s = src + (size_t)z * KD * RR + (size_t)kb * RR + r;
  unsigned short t[8];
  #pragma unroll
  for (int j = 0; j < 8; ++j) t[j] = f2bf(s[(size_t)j * RR]);
  *(uint4*)(dst + (size_t)z * KD * RR + (size_t)cl * 512 + lane * 8) = *(uint4*)t;
}

// ---------------- router: logits (fp32), top-2, softmax, aux stats ----------------
#define R_BLOCKS 128
#define R_TPW    (N_TOK / (R_BLOCKS * 4))   // 16 tokens per wave
__global__ __launch_bounds__(256) void router_kernel(
    const float* __restrict__ x, const float* __restrict__ gW, const float* __restrict__ gb,
    int* __restrict__ tok_e, float* __restrict__ tok_g,
    int* __restrict__ cnt, float* __restrict__ imp, float* __restrict__ ent_sum) {
  __shared__ int s_cnt[NE];
  __shared__ float s_imp[NE];
  __shared__ float s_ent;
  int tid = threadIdx.x;
  if (tid < NE) { s_cnt[tid] = 0; s_imp[tid] = 0.f; }
  if (tid == 0) s_ent = 0.f;
  __syncthreads();
  int wid = tid >> 6, lane = tid & 63;
  int t0 = (blockIdx.x * 4 + wid) * R_TPW;
  float imp_loc[8] = {0.f, 0.f, 0.f, 0.f, 0.f, 0.f, 0.f, 0.f};
  float ent_loc = 0.f;
  for (int t = 0; t < R_TPW; ++t) {
    int n = t0 + t;
    const float* xr = x + (size_t)n * DIM;
    float p[8] = {0.f, 0.f, 0.f, 0.f, 0.f, 0.f, 0.f, 0.f};
    #pragma unroll
    for (int it = 0; it < DIM / 64; ++it) {
      int d = lane + (it << 6);
      float xv = xr[d];
      const float4* g4 = (const float4*)(gW + (size_t)d * NE);
      float4 a = g4[0], b = g4[1];
      p[0] += xv * a.x; p[1] += xv * a.y; p[2] += xv * a.z; p[3] += xv * a.w;
      p[4] += xv * b.x; p[5] += xv * b.y; p[6] += xv * b.z; p[7] += xv * b.w;
    }
    #pragma unroll
    for (int e = 0; e < 8; ++e)
      for (int o = 32; o > 0; o >>= 1) p[e] += __shfl_down(p[e], o, 64);
    if (lane == 0) {
      float lg[8];
      #pragma unroll
      for (int e = 0; e < 8; ++e) lg[e] = p[e] + gb[e];
      int i0 = 0;
      #pragma unroll
      for (int e = 1; e < 8; ++e) if (lg[e] > lg[i0]) i0 = e;   // ties -> lowest idx
      int i1 = (i0 == 0) ? 1 : 0;
      #pragma unroll
      for (int e = 0; e < 8; ++e) if (e != i0 && lg[e] > lg[i1]) i1 = e;
      float d1 = expf(lg[i1] - lg[i0]);
      float g0 = 1.f / (1.f + d1);
      float g1 = d1 * g0;
      tok_e[2 * n] = i0; tok_e[2 * n + 1] = i1;
      tok_g[2 * n] = g0; tok_g[2 * n + 1] = g1;
      atomicAdd(&s_cnt[i0], 1);
      atomicAdd(&s_cnt[i1], 1);
      float mx = lg[i0], s = 0.f, pe[8];
      #pragma unroll
      for (int e = 0; e < 8; ++e) { pe[e] = expf(lg[e] - mx); s += pe[e]; }
      float inv = 1.f / s;
      #pragma unroll
      for (int e = 0; e < 8; ++e) {
        float pr = pe[e] * inv;
        imp_loc[e] += pr;
        ent_loc -= pr * logf(pr + 1e-8f);
      }
    }
  }
  if (lane == 0) {
    #pragma unroll
    for (int e = 0; e < 8; ++e) atomicAdd(&s_imp[e], imp_loc[e]);
    atomicAdd(&s_ent, ent_loc);
  }
  __syncthreads();
  const float invN = 1.f / (float)N_TOK;
  if (tid < NE) {
    atomicAdd(&cnt[tid], s_cnt[tid]);
    atomicAdd(&imp[tid], s_imp[tid] * invN);
  }
  if (tid == NE) atomicAdd(ent_sum, s_ent * invN);
}

// ---------------- finalize: padded offsets/cursors + scalar outputs ----------------
__global__ void finalize_kernel(const int* __restrict__ cnt, int* __restrict__ poffs,
                                int* __restrict__ cursor, const float* __restrict__ imp,
                                const float* __restrict__ ent_sum, float* __restrict__ out_tail) {
  if (threadIdx.x == 0) {
    int off = 0; float bal = 0.f, util = 0.f;
    for (int e = 0; e < NE; ++e) {
      poffs[e] = off; cursor[e] = off;
      off += ((cnt[e] + 127) >> 7) << 7;   // 128-aligned region per expert
      float ld = (float)cnt[e] * (1.f / (float)N_TOK);
      float im = imp[e];
      out_tail[3 + e] = ld;        // load
      out_tail[11 + e] = im;       // importance
      bal += im * ld;
      util -= ld * logf(ld + 1e-8f);
    }
    poffs[NE] = off;
    out_tail[0] = (float)NE * bal; // balance_loss
    out_tail[1] = *ent_sum;        // entropy
    out_tail[2] = util;            // utilization_entropy
  }
}

// ---------------- scatter pairs into (padded) expert buckets ----------------
__global__ __launch_bounds__(256) void scatter_kernel(
    const int* __restrict__ tok_e, const float* __restrict__ tok_g,
    int* __restrict__ cursor, int* __restrict__ row_token, float* __restrict__ row_gate,
    int* __restrict__ pair_slot) {
  __shared__ int s_cnt[NE], s_base[NE], s_rank[NE];
  int tid = threadIdx.x;
  if (tid < NE) { s_cnt[tid] = 0; s_rank[tid] = 0; }
  __syncthreads();
  int n = blockIdx.x * 256 + tid;
  int e0 = tok_e[2 * n], e1 = tok_e[2 * n + 1];
  atomicAdd(&s_cnt[e0], 1);
  atomicAdd(&s_cnt[e1], 1);
  __syncthreads();
  if (tid < NE) s_base[tid] = atomicAdd(&cursor[tid], s_cnt[tid]);
  __syncthreads();
  int r0 = atomicAdd(&s_rank[e0], 1);
  int s0 = s_base[e0] + r0;
  row_token[s0] = n; row_gate[s0] = tok_g[2 * n]; pair_slot[2 * n] = s0;
  int r1 = atomicAdd(&s_rank[e1], 1);
  int s1 = s_base[e1] + r1;
  row_token[s1] = n; row_gate[s1] = tok_g[2 * n + 1]; pair_slot[2 * n + 1] = s1;
}

// ---------------- gather bucketed A (x rows -> frag-chunk bf16, Kd=1024) ----------------
__global__ __launch_bounds__(256) void gather_a1(
    const float* __restrict__ x, const int* __restrict__ row_token,
    const int* __restrict__ cnt, const int* __restrict__ poffs,
    unsigned short* __restrict__ Ab1) {
  int e = blockIdx.z;
  int base = poffs[e];
  int pcnt = poffs[e + 1] - base;
  int nch = (pcnt >> 4) * 32;
  int cl = blockIdx.x * 4 + (threadIdx.x >> 6);
  if (cl >= nch) return;
  int lane = threadIdx.x & 63, m16 = lane & 15, q = lane >> 4;
  int rblk = cl >> 5, kblk = cl & 31;
  int sl = rblk * 16 + m16;
  int slot = base + sl;
  int tok = (sl < cnt[e]) ? row_token[slot] : 0;   // pad rows: token 0 (finite)
  int k = kblk * 32 + q * 8;
  const float4* sp = (const float4*)(x + (size_t)tok * DIM + k);
  float4 v0 = sp[0], v1 = sp[1];
  unsigned short t[8] = {f2bf(v0.x), f2bf(v0.y), f2bf(v0.z), f2bf(v0.w),
                         f2bf(v1.x), f2bf(v1.y), f2bf(v1.z), f2bf(v1.w)};
  *(uint4*)(Ab1 + ((size_t)(slot >> 4) * 32 + kblk) * 512 + lane * 8) = *(uint4*)t;
}

#define GEMM_BLOCKS 1024   // 4 blocks/CU x 256 CU = guaranteed co-resident (R9-proven)

// XCD-bijective swizzle (T1): 1024 % 8 == 0 so the simple form is bijective.
__device__ __forceinline__ int xcd_swz(int bid) {
  return (bid & 7) * (GEMM_BLOCKS >> 3) + (bid >> 3);
}

// ---------------- fused expert MLP: gemm1 (+gelu) and gemm2, overlapped ----------------
// Unit list per rt (32 units): [16 g1 tiles][8 g2 tiles x 2]. Contiguous weighted
// ranges per block; per-rt rdy counters gate g2 (and the yb-over-Ab1 alias).
__global__ __launch_bounds__(256, 4) void expert_mlp(
    const unsigned short* __restrict__ Ab1,   // frag, Kd32=32 (aliased by yb)
    const unsigned short* __restrict__ W1f,   // [E] frag, rows=HID, Kd32=32
    const float* __restrict__ b1,             // [E][H]
    const unsigned short* __restrict__ W2f,   // [E] frag, rows=DIM, Kd32=64
    const int* __restrict__ poffs,
    unsigned short* __restrict__ He,          // frag, rows=CAPP, Kd32=64
    unsigned short* __restrict__ yb,          // [CAPP][DIM] row-major (= Ab1)
    int* __restrict__ rdy) {                  // [nrt] ready counters (zeroed)
  __shared__ __align__(16) unsigned short As[8192], Bs[8192];   // exactly 32KB
  int tid = threadIdx.x, wid = tid >> 6, lane = tid & 63;
  int m16 = lane & 15, q = lane >> 4;
  int wr = (wid & 1) << 6, wc = (wid >> 1) << 6;
  int ra = wr >> 4, rc = wc >> 4;
  unsigned short* lA = As + wid * 4 * 512;
  unsigned short* lB = Bs + wid * 4 * 512;
  f32x4_t zero4 = {0.f, 0.f, 0.f, 0.f};
  int nrt = poffs[NE] >> 7;
  int W = nrt << 5;                           // total units
  int swz = xcd_swz(blockIdx.x);
  int lo = (int)(((long long)swz * W) / GEMM_BLOCKS);
  int hi = (int)(((long long)(swz + 1) * W) / GEMM_BLOCKS);

  for (int u = lo; u < hi; ++u) {
    int rt = u >> 5, r = u & 31;
    int row0 = rt << 7;
    int e = 0;
    #pragma unroll
    for (int k = 1; k < NE; ++k) e += (poffs[k] <= row0) ? 1 : 0;   // monotone scan

    if (r < 16) {
      // ================= gemm1 tile (rt, ct=r): He = gelu(Ab1 @ W1f + b1) =================
      int col0 = r << 7;
      const unsigned short* Ag = Ab1 + ((size_t)((rt << 3) + wid * 2) * 32) * 512 + lane * 8;
      const unsigned short* Bg = W1f + (size_t)e * HID * DIM
                               + ((size_t)((col0 >> 4) + wid * 2) * 32) * 512 + lane * 8;
      f32x4_t acc[4][4];
      #pragma unroll
      for (int i = 0; i < 4; ++i)
        #pragma unroll
        for (int j = 0; j < 4; ++j) acc[i][j] = zero4;

      for (int k0 = 0; k0 < DIM; k0 += 64) {
        int kc = (k0 >> 5) * 512;
        load16_lds(Ag + kc,                  lA);
        load16_lds(Ag + kc + 512,            lA + 512);
        load16_lds(Ag + kc + 32 * 512,       lA + 1024);
        load16_lds(Ag + kc + 32 * 512 + 512, lA + 1536);
        load16_lds(Bg + kc,                  lB);
        load16_lds(Bg + kc + 512,            lB + 512);
        load16_lds(Bg + kc + 32 * 512,       lB + 1024);
        load16_lds(Bg + kc + 32 * 512 + 512, lB + 1536);
        __syncthreads();
        #pragma unroll
        for (int ks = 0; ks < 2; ++ks) {
          bf16x8_t a[4], b[4];
          #pragma unroll
          for (int i = 0; i < 4; ++i) {
            a[i] = *(const bf16x8_t*)&As[((ra + i) * 2 + ks) * 512 + lane * 8];
            b[i] = *(const bf16x8_t*)&Bs[((rc + i) * 2 + ks) * 512 + lane * 8];
          }
          #pragma unroll
          for (int i = 0; i < 4; ++i)
            #pragma unroll
            for (int j = 0; j < 4; ++j)
              acc[i][j] = __builtin_amdgcn_mfma_f32_16x16x32_bf16(a[i], b[j], acc[i][j], 0, 0, 0);
        }
        __syncthreads();
      }

      const float* b1e = b1 + (size_t)e * HID;
      int sb = rt << 3;
      #pragma unroll
      for (int i = 0; i < 4; ++i) {
        size_t sblk = (size_t)(sb + ra + i);
        #pragma unroll
        for (int rr = 0; rr < 4; ++rr) {
          int s15 = q * 4 + rr;   // slot & 15
          #pragma unroll
          for (int j = 0; j < 4; ++j) {
            int col = col0 + wc + j * 16 + m16;
            float v = acc[i][j][rr] + b1e[col];
            size_t off = (sblk * 64 + (col >> 5)) * 512 + (((col >> 3) & 3) * 16 + s15) * 8 + (col & 7);
            He[off] = f2bf(gelu_exact(v));
          }
        }
      }
      // publish: all stores drained -> block barrier -> device fence -> count
      asm volatile("s_waitcnt vmcnt(0)" ::: "memory");
      __syncthreads();
      if (tid == 0) {
        __threadfence();
        atomicAdd(&rdy[rt], 1);
      }
    } else if (!(r & 1)) {
      // ================= gemm2 tile (rt, ct): yb = He @ W2f =================
      int ct = (r - 16) >> 1;
      int col0 = ct << 7;
      if (tid == 0) {
        int guard = 0;
        while (atomicAdd(&rdy[rt], 0) < 16 && guard < (1 << 22)) {   // valve: fail visibly, not hang
          __builtin_amdgcn_s_sleep(8);
          ++guard;
        }
        __threadfence();   // acquire: invalidate stale cached He
      }
      __syncthreads();

      const unsigned short* Ag = He + ((size_t)((rt << 3) + wid * 2) * 64) * 512 + lane * 8;
      const unsigned short* Bg = W2f + (size_t)e * DIM * HID
                               + ((size_t)((col0 >> 4) + wid * 2) * 64) * 512 + lane * 8;
      f32x4_t acc[4][4];
      #pragma unroll
      for (int i = 0; i < 4; ++i)
        #pragma unroll
        for (int j = 0; j < 4; ++j) acc[i][j] = zero4;

      for (int k0 = 0; k0 < HID; k0 += 64) {
        int kc = (k0 >> 5) * 512;
        load16_lds(Ag + kc,                  lA);
        load16_lds(Ag + kc + 512,            lA + 512);
        load16_lds(Ag + kc + 64 * 512,       lA + 1024);
        load16_lds(Ag + kc + 64 * 512 + 512, lA + 1536);
        load16_lds(Bg + kc,                  lB);
        load16_lds(Bg + kc + 512,            lB + 512);
        load16_lds(Bg + kc + 64 * 512,       lB + 1024);
        load16_lds(Bg + kc + 64 * 512 + 512, lB + 1536);
        __syncthreads();
        #pragma unroll
        for (int ks = 0; ks < 2; ++ks) {
          bf16x8_t a[4], b[4];
          #pragma unroll
          for (int i = 0; i < 4; ++i) {
            a[i] = *(const bf16x8_t*)&As[((ra + i) * 2 + ks) * 512 + lane * 8];
            b[i] = *(const bf16x8_t*)&Bs[((rc + i) * 2 + ks) * 512 + lane * 8];
          }
          #pragma unroll
          for (int i = 0; i < 4; ++i)
            #pragma unroll
            for (int j = 0; j < 4; ++j)
              acc[i][j] = __builtin_amdgcn_mfma_f32_16x16x32_bf16(a[i], b[j], acc[i][j], 0, 0, 0);
        }
        __syncthreads();
      }

      #pragma unroll
      for (int i = 0; i < 4; ++i) {
        #pragma unroll
        for (int rr = 0; rr < 4; ++rr) {
          size_t slot = (size_t)(row0 + wr + i * 16 + q * 4 + rr);
          #pragma unroll
          for (int j = 0; j < 4; ++j) {
            int col = col0 + wc + j * 16 + m16;
            yb[slot * DIM + col] = f2bf(acc[i][j][rr]);
          }
        }
      }
    }
    // odd r>=16: tile owned via its even unit; nothing to do
  }
}

// ---------------- gather + gate + bias + residual + LayerNorm ----------------
__global__ __launch_bounds__(256) void ln_kernel(
    const float* __restrict__ x, const unsigned short* __restrict__ yb,
    const int* __restrict__ tok_e, const float* __restrict__ tok_g,
    const int* __restrict__ pair_slot, const float* __restrict__ b2,
    const float* __restrict__ gamma, const float* __restrict__ beta,
    float* __restrict__ out) {
  int n = blockIdx.x, tid = threadIdx.x;
  int e0 = tok_e[2 * n], e1 = tok_e[2 * n + 1];
  float g0 = tok_g[2 * n], g1 = tok_g[2 * n + 1];
  size_t s0 = (size_t)pair_slot[2 * n], s1 = (size_t)pair_slot[2 * n + 1];
  const float* xr = x + (size_t)n * DIM;
  const unsigned short* y0 = yb + s0 * DIM;
  const unsigned short* y1 = yb + s1 * DIM;
  const float* b2e0 = b2 + (size_t)e0 * DIM;
  const float* b2e1 = b2 + (size_t)e1 * DIM;
  float z[4], s = 0.f, s2 = 0.f;
  #pragma unroll
  for (int jj = 0; jj < 4; ++jj) {
    int d = tid + (jj << 8);
    float v = xr[d] + g0 * (bf2f(y0[d]) + b2e0[d]) + g1 * (bf2f(y1[d]) + b2e1[d]);
    z[jj] = v; s += v; s2 += v * v;
  }
  for (int o = 32; o > 0; o >>= 1) { s += __shfl_down(s, o, 64); s2 += __shfl_down(s2, o, 64); }
  __shared__ float rs[4], rs2[4];
  int wid = tid >> 6, lane = tid & 63;
  if (lane == 0) { rs[wid] = s; rs2[wid] = s2; }
  __syncthreads();
  float ts = rs[0] + rs[1] + rs[2] + rs[3];
  float ts2 = rs2[0] + rs2[1] + rs2[2] + rs2[3];
  float mu = ts * (1.f / DIM);
  float var = ts2 * (1.f / DIM) - mu * mu;
  float rstd = rsqrtf(var + 1e-5f);
  float* orow = out + (size_t)n * DIM;
  #pragma unroll
  for (int jj = 0; jj < 4; ++jj) {
    int d = tid + (jj << 8);
    orow[d] = (z[jj] - mu) * rstd * gamma[d] + beta[d];
  }
}

extern "C" void kernel_launch(void* const* d_in, const int* in_sizes, int n_in,
                              void* d_out, int out_size, void* d_ws, size_t ws_size,
                              hipStream_t stream) {
  const float* x     = (const float*)d_in[0];
  const float* gW    = (const float*)d_in[1];
  const float* gb    = (const float*)d_in[2];
  const float* W1    = (const float*)d_in[3];
  const float* b1    = (const float*)d_in[4];
  const float* W2    = (const float*)d_in[5];
  const float* b2    = (const float*)d_in[6];
  const float* gamma = (const float*)d_in[7];
  const float* beta  = (const float*)d_in[8];
  float* out = (float*)d_out;

  // workspace layout (~166 MB), all chunks 16B-aligned
  char* w = (char*)d_ws;
  unsigned short* W1f = (unsigned short*)w; w += (size_t)NE * HID * DIM * 2;
  unsigned short* W2f = (unsigned short*)w; w += (size_t)NE * DIM * HID * 2;
  unsigned short* He  = (unsigned short*)w; w += (size_t)CAPP * HID * 2;
  unsigned short* AbY = (unsigned short*)w; w += (size_t)CAPP * DIM * 2;  // Ab1, then yb (aliased)
  int*   row_token    = (int*)w;            w += (size_t)CAPP * 4;
  float* row_gate     = (float*)w;          w += (size_t)CAPP * 4;
  int*   tok_e        = (int*)w;            w += (size_t)NPAIR * 4;
  float* tok_g        = (float*)w;          w += (size_t)NPAIR * 4;
  int*   pair_slot    = (int*)w;            w += (size_t)NPAIR * 4;
  float* imp          = (float*)w;          // 8 floats            [byte   0)
  float* ent_sum      = imp + 8;            // 1 float (+pad)      [byte  32)
  int*   cntp         = (int*)(imp + 16);   // 8 ints              [byte  64)
  int*   cursor       = cntp + 8;           // 8 ints              [byte  96)
  int*   poffs        = cursor + 8;         // 9 ints              [byte 128)
  int*   rdy          = (int*)(imp + 64);   // up to 136 ints      [byte 256)

  unsigned short* Ab1 = AbY;                // gemm1 input (per-rt dead before yb write)
  unsigned short* yb  = AbY;                // gemm2 output (gated by rdy[rt]==16)

  hipMemsetAsync(imp, 0, 1024, stream);     // imp, ent_sum, cnt, cursors, rdy

  w_to_frag<DIM, HID><<<dim3(1024, 1, NE), 256, 0, stream>>>(W1, W1f);
  w_to_frag<HID, DIM><<<dim3(1024, 1, NE), 256, 0, stream>>>(W2, W2f);
  router_kernel<<<R_BLOCKS, 256, 0, stream>>>(x, gW, gb, tok_e, tok_g, cntp, imp, ent_sum);
  finalize_kernel<<<1, 64, 0, stream>>>(cntp, poffs, cursor, imp, ent_sum, out + TAIL);
  scatter_kernel<<<N_TOK / 256, 256, 0, stream>>>(tok_e, tok_g, cursor, row_token, row_gate, pair_slot);
  gather_a1<<<dim3(4096, 1, NE), 256, 0, stream>>>(x, row_token, cntp, poffs, Ab1);
  expert_mlp<<<GEMM_BLOCKS, 256, 0, stream>>>(Ab1, W1f, b1, W2f, poffs, He, yb, rdy);
  ln_kernel<<<N_TOK, 256, 0, stream>>>(x, yb, tok_e, tok_g, pair_slot, b2, gamma, beta, out);
}

// Round 8
// 486.235 us; speedup vs baseline: 2.1189x; 2.1189x over previous
//
#include <hip/hip_runtime.h>
#include <math.h>

#define N_TOK 8192
#define DIM   1024
#define HID   2048
#define NE    8
#define NPAIR (N_TOK * 2)          // 16384 (token, expert) pairs exactly
#define CAPP  (NPAIR + NE * 128)   // 17408: expert regions padded to 128 rows
#define TAIL  (N_TOK * DIM)        // offset of scalar outputs in d_out

typedef __bf16 bf16x8_t __attribute__((ext_vector_type(8)));
typedef float  f32x4_t  __attribute__((ext_vector_type(4)));

__device__ __forceinline__ unsigned short f2bf(float f) {
  union { float f; unsigned u; } v; v.f = f;
  unsigned r = v.u + 0x7fffu + ((v.u >> 16) & 1u);   // RNE
  return (unsigned short)(r >> 16);
}

__device__ __forceinline__ float bf2f(unsigned short h) {
  union { unsigned u; float f; } v; v.u = ((unsigned)h) << 16;
  return v.f;
}

__device__ __forceinline__ float gelu_exact(float v) {
  return 0.5f * v * (1.f + erff(v * 0.70710678118654752440f));
}

// async global->LDS DMA, 16B/lane; LDS base wave-uniform, HW scatters lane*16.
__device__ __forceinline__ void load16_lds(const void* g, void* l) {
  __builtin_amdgcn_global_load_lds(
      (const __attribute__((address_space(1))) unsigned int*)g,
      (__attribute__((address_space(3))) unsigned int*)l, 16, 0, 0);
}

// =======================================================================
// Fragment-chunk global layout (R4): a matrix [R rows][Kd k] is stored as
// 1KB chunks; chunk c = (r>>4)*(Kd/32) + (k>>5); within a chunk, lane
// l = (k>>3&3)*16 + (r&15) owns 16B = 8 shorts (k&7 fastest). A GEMM tile
// stage is ONE contiguous-1KB global_load_lds per chunk and fragment
// ds_read_b128 is sequential (0 bank conflicts, proven R3).
//
// R11 post-mortem: in-kernel g1->g2 dependency (rdy spin) serialized the
// grid into a chain (767us). Sync-structure fusion abandoned.
//
// R12: GEMMs are byte-for-byte R9 (persistent 1024 blocks = 4/CU hard
// cap, stride tile loop, XCD-bijective swizzle -> 479us proven). New:
// (a) w_to_frag rewritten for full coalescing -- old version read 8
// floats/thread at 8KB stride (16-lane x 64B segments, ~1/4 BW on 128MB
// of weights); new version reads 1KB-contiguous rows into a padded LDS
// tile ([256][34] bf16, 17-bank stride = conflict-free) and emits the
// same chunks as uint4 stores. (b) ln_kernel vectorized: float4/ushort4
// loads (thread owns 4 consecutive elems) instead of scalar u16 yb reads.
// =======================================================================

// ---------------- weights fp32 [z][Kd][R] -> frag-chunk bf16 (coalesced) ----------------
// grid: (RR/256, KD/32, NE); block 256.
template<int KD, int RR>
__global__ __launch_bounds__(256) void w_to_frag(const float* __restrict__ src,
                                                 unsigned short* __restrict__ dst) {
  constexpr int KD32 = KD / 32;
  __shared__ unsigned short L[256][34];   // [r][kk], +2 pad -> 17-bank stride
  int z = blockIdx.z, kblk = blockIdx.y;
  int r0 = blockIdx.x << 8;
  int t = threadIdx.x;
  const float* s = src + (size_t)z * KD * RR + (size_t)(kblk * 32) * RR + r0 + t;
  #pragma unroll
  for (int kk = 0; kk < 32; ++kk)
    L[t][kk] = f2bf(s[(size_t)kk * RR]);   // 256 consecutive floats per kk: 1KB coalesced
  __syncthreads();
  int lane = t & 63, m16 = lane & 15, q = lane >> 4;
  unsigned short* d = dst + (size_t)z * KD * RR;
  #pragma unroll
  for (int p = 0; p < 4; ++p) {
    int ci = p * 4 + (t >> 6);            // chunk-in-block 0..15
    int c = ((r0 >> 4) + ci) * KD32 + kblk;
    uint4 v = *(const uint4*)&L[ci * 16 + m16][q * 8];   // 8 shorts k = q*8..q*8+7
    *(uint4*)(d + (size_t)c * 512 + lane * 8) = v;
  }
}

// ---------------- router: logits (fp32), top-2, softmax, aux stats ----------------
#define R_BLOCKS 128
#define R_TPW    (N_TOK / (R_BLOCKS * 4))   // 16 tokens per wave
__global__ __launch_bounds__(256) void router_kernel(
    const float* __restrict__ x, const float* __restrict__ gW, const float* __restrict__ gb,
    int* __restrict__ tok_e, float* __restrict__ tok_g,
    int* __restrict__ cnt, float* __restrict__ imp, float* __restrict__ ent_sum) {
  __shared__ int s_cnt[NE];
  __shared__ float s_imp[NE];
  __shared__ float s_ent;
  int tid = threadIdx.x;
  if (tid < NE) { s_cnt[tid] = 0; s_imp[tid] = 0.f; }
  if (tid == 0) s_ent = 0.f;
  __syncthreads();
  int wid = tid >> 6, lane = tid & 63;
  int t0 = (blockIdx.x * 4 + wid) * R_TPW;
  float imp_loc[8] = {0.f, 0.f, 0.f, 0.f, 0.f, 0.f, 0.f, 0.f};
  float ent_loc = 0.f;
  for (int t = 0; t < R_TPW; ++t) {
    int n = t0 + t;
    const float* xr = x + (size_t)n * DIM;
    float p[8] = {0.f, 0.f, 0.f, 0.f, 0.f, 0.f, 0.f, 0.f};
    #pragma unroll
    for (int it = 0; it < DIM / 64; ++it) {
      int d = lane + (it << 6);
      float xv = xr[d];
      const float4* g4 = (const float4*)(gW + (size_t)d * NE);
      float4 a = g4[0], b = g4[1];
      p[0] += xv * a.x; p[1] += xv * a.y; p[2] += xv * a.z; p[3] += xv * a.w;
      p[4] += xv * b.x; p[5] += xv * b.y; p[6] += xv * b.z; p[7] += xv * b.w;
    }
    #pragma unroll
    for (int e = 0; e < 8; ++e)
      for (int o = 32; o > 0; o >>= 1) p[e] += __shfl_down(p[e], o, 64);
    if (lane == 0) {
      float lg[8];
      #pragma unroll
      for (int e = 0; e < 8; ++e) lg[e] = p[e] + gb[e];
      int i0 = 0;
      #pragma unroll
      for (int e = 1; e < 8; ++e) if (lg[e] > lg[i0]) i0 = e;   // ties -> lowest idx
      int i1 = (i0 == 0) ? 1 : 0;
      #pragma unroll
      for (int e = 0; e < 8; ++e) if (e != i0 && lg[e] > lg[i1]) i1 = e;
      float d1 = expf(lg[i1] - lg[i0]);
      float g0 = 1.f / (1.f + d1);
      float g1 = d1 * g0;
      tok_e[2 * n] = i0; tok_e[2 * n + 1] = i1;
      tok_g[2 * n] = g0; tok_g[2 * n + 1] = g1;
      atomicAdd(&s_cnt[i0], 1);
      atomicAdd(&s_cnt[i1], 1);
      float mx = lg[i0], s = 0.f, pe[8];
      #pragma unroll
      for (int e = 0; e < 8; ++e) { pe[e] = expf(lg[e] - mx); s += pe[e]; }
      float inv = 1.f / s;
      #pragma unroll
      for (int e = 0; e < 8; ++e) {
        float pr = pe[e] * inv;
        imp_loc[e] += pr;
        ent_loc -= pr * logf(pr + 1e-8f);
      }
    }
  }
  if (lane == 0) {
    #pragma unroll
    for (int e = 0; e < 8; ++e) atomicAdd(&s_imp[e], imp_loc[e]);
    atomicAdd(&s_ent, ent_loc);
  }
  __syncthreads();
  const float invN = 1.f / (float)N_TOK;
  if (tid < NE) {
    atomicAdd(&cnt[tid], s_cnt[tid]);
    atomicAdd(&imp[tid], s_imp[tid] * invN);
  }
  if (tid == NE) atomicAdd(ent_sum, s_ent * invN);
}

// ---------------- finalize: padded offsets/cursors + scalar outputs ----------------
__global__ void finalize_kernel(const int* __restrict__ cnt, int* __restrict__ poffs,
                                int* __restrict__ cursor, const float* __restrict__ imp,
                                const float* __restrict__ ent_sum, float* __restrict__ out_tail) {
  if (threadIdx.x == 0) {
    int off = 0; float bal = 0.f, util = 0.f;
    for (int e = 0; e < NE; ++e) {
      poffs[e] = off; cursor[e] = off;
      off += ((cnt[e] + 127) >> 7) << 7;   // 128-aligned region per expert
      float ld = (float)cnt[e] * (1.f / (float)N_TOK);
      float im = imp[e];
      out_tail[3 + e] = ld;        // load
      out_tail[11 + e] = im;       // importance
      bal += im * ld;
      util -= ld * logf(ld + 1e-8f);
    }
    poffs[NE] = off;
    out_tail[0] = (float)NE * bal; // balance_loss
    out_tail[1] = *ent_sum;        // entropy
    out_tail[2] = util;            // utilization_entropy
  }
}

// ---------------- scatter pairs into (padded) expert buckets ----------------
__global__ __launch_bounds__(256) void scatter_kernel(
    const int* __restrict__ tok_e, const float* __restrict__ tok_g,
    int* __restrict__ cursor, int* __restrict__ row_token, float* __restrict__ row_gate,
    int* __restrict__ pair_slot) {
  __shared__ int s_cnt[NE], s_base[NE], s_rank[NE];
  int tid = threadIdx.x;
  if (tid < NE) { s_cnt[tid] = 0; s_rank[tid] = 0; }
  __syncthreads();
  int n = blockIdx.x * 256 + tid;
  int e0 = tok_e[2 * n], e1 = tok_e[2 * n + 1];
  atomicAdd(&s_cnt[e0], 1);
  atomicAdd(&s_cnt[e1], 1);
  __syncthreads();
  if (tid < NE) s_base[tid] = atomicAdd(&cursor[tid], s_cnt[tid]);
  __syncthreads();
  int r0 = atomicAdd(&s_rank[e0], 1);
  int s0 = s_base[e0] + r0;
  row_token[s0] = n; row_gate[s0] = tok_g[2 * n]; pair_slot[2 * n] = s0;
  int r1 = atomicAdd(&s_rank[e1], 1);
  int s1 = s_base[e1] + r1;
  row_token[s1] = n; row_gate[s1] = tok_g[2 * n + 1]; pair_slot[2 * n + 1] = s1;
}

// ---------------- gather bucketed A (x rows -> frag-chunk bf16, Kd=1024) ----------------
__global__ __launch_bounds__(256) void gather_a1(
    const float* __restrict__ x, const int* __restrict__ row_token,
    const int* __restrict__ cnt, const int* __restrict__ poffs,
    unsigned short* __restrict__ Ab1) {
  int e = blockIdx.z;
  int base = poffs[e];
  int pcnt = poffs[e + 1] - base;
  int nch = (pcnt >> 4) * 32;
  int cl = blockIdx.x * 4 + (threadIdx.x >> 6);
  if (cl >= nch) return;
  int lane = threadIdx.x & 63, m16 = lane & 15, q = lane >> 4;
  int rblk = cl >> 5, kblk = cl & 31;
  int sl = rblk * 16 + m16;
  int slot = base + sl;
  int tok = (sl < cnt[e]) ? row_token[slot] : 0;   // pad rows: token 0 (finite)
  int k = kblk * 32 + q * 8;
  const float4* sp = (const float4*)(x + (size_t)tok * DIM + k);
  float4 v0 = sp[0], v1 = sp[1];
  unsigned short t[8] = {f2bf(v0.x), f2bf(v0.y), f2bf(v0.z), f2bf(v0.w),
                         f2bf(v1.x), f2bf(v1.y), f2bf(v1.z), f2bf(v1.w)};
  *(uint4*)(Ab1 + ((size_t)(slot >> 4) * 32 + kblk) * 512 + lane * 8) = *(uint4*)t;
}

#define GEMM_BLOCKS 1024   // 4 blocks/CU x 256 CU (hard cap: 128 regs/wave, m69)

// XCD-bijective swizzle (T1): 1024 % 8 == 0 so the simple form is bijective.
__device__ __forceinline__ int xcd_swz(int bid) {
  return (bid & 7) * (GEMM_BLOCKS >> 3) + (bid >> 3);
}

// ---------------- GEMM1: He = gelu(Ab1 @ W1f + b1), He in frag order (Kd=2048) ----------------
// Persistent grid; R4 inner loop: 128x128 tile, 4 waves, 64x64/wave, BK=64. (R9-exact)
__global__ __launch_bounds__(256, 4) void expert_gemm1(
    const unsigned short* __restrict__ Ab1,   // frag, Kd32=32
    const unsigned short* __restrict__ W1f,   // [E] frag, rows=HID, Kd32=32
    const float* __restrict__ b1,             // [E][H]
    const int* __restrict__ poffs,
    unsigned short* __restrict__ He) {        // frag, rows=CAPP, Kd32=64
  __shared__ __align__(16) unsigned short As[8192], Bs[8192];
  __shared__ int s_po[NE + 1];
  int tid = threadIdx.x, wid = tid >> 6, lane = tid & 63;
  if (tid <= NE) s_po[tid] = poffs[tid];
  __syncthreads();
  int nt = (s_po[NE] >> 7) << 4;              // row-tiles(128) x 16 col-tiles
  int m16 = lane & 15, q = lane >> 4;
  int wr = (wid & 1) << 6, wc = (wid >> 1) << 6;
  int ra = wr >> 4, rc = wc >> 4;
  unsigned short* lA = As + wid * 4 * 512;
  unsigned short* lB = Bs + wid * 4 * 512;
  f32x4_t zero4 = {0.f, 0.f, 0.f, 0.f};
  int bid0 = xcd_swz(blockIdx.x);

  for (int tile = bid0; tile < nt; tile += GEMM_BLOCKS) {
    int rt = tile >> 4, ct = tile & 15;
    int col0 = ct << 7;
    int row0 = rt << 7;                       // absolute slot row (region-aligned)
    int e = 0;
    while (e + 1 < NE && s_po[e + 1] <= row0) ++e;
    const unsigned short* Ag = Ab1 + ((size_t)((rt << 3) + wid * 2) * 32) * 512 + lane * 8;
    const unsigned short* Bg = W1f + (size_t)e * HID * DIM
                             + ((size_t)((col0 >> 4) + wid * 2) * 32) * 512 + lane * 8;
    f32x4_t acc[4][4];
    #pragma unroll
    for (int i = 0; i < 4; ++i)
      #pragma unroll
      for (int j = 0; j < 4; ++j) acc[i][j] = zero4;

    for (int k0 = 0; k0 < DIM; k0 += 64) {
      int kc = (k0 >> 5) * 512;
      load16_lds(Ag + kc,                  lA);
      load16_lds(Ag + kc + 512,            lA + 512);
      load16_lds(Ag + kc + 32 * 512,       lA + 1024);
      load16_lds(Ag + kc + 32 * 512 + 512, lA + 1536);
      load16_lds(Bg + kc,                  lB);
      load16_lds(Bg + kc + 512,            lB + 512);
      load16_lds(Bg + kc + 32 * 512,       lB + 1024);
      load16_lds(Bg + kc + 32 * 512 + 512, lB + 1536);
      __syncthreads();
      #pragma unroll
      for (int ks = 0; ks < 2; ++ks) {
        bf16x8_t a[4], b[4];
        #pragma unroll
        for (int i = 0; i < 4; ++i) {
          a[i] = *(const bf16x8_t*)&As[((ra + i) * 2 + ks) * 512 + lane * 8];
          b[i] = *(const bf16x8_t*)&Bs[((rc + i) * 2 + ks) * 512 + lane * 8];
        }
        #pragma unroll
        for (int i = 0; i < 4; ++i)
          #pragma unroll
          for (int j = 0; j < 4; ++j)
            acc[i][j] = __builtin_amdgcn_mfma_f32_16x16x32_bf16(a[i], b[j], acc[i][j], 0, 0, 0);
      }
      __syncthreads();
    }

    const float* b1e = b1 + (size_t)e * HID;
    int sb = rt << 3;
    #pragma unroll
    for (int i = 0; i < 4; ++i) {
      size_t sblk = (size_t)(sb + ra + i);
      #pragma unroll
      for (int rr = 0; rr < 4; ++rr) {
        int s15 = q * 4 + rr;   // slot & 15
        #pragma unroll
        for (int j = 0; j < 4; ++j) {
          int col = col0 + wc + j * 16 + m16;
          float v = acc[i][j][rr] + b1e[col];
          size_t off = (sblk * 64 + (col >> 5)) * 512 + (((col >> 3) & 3) * 16 + s15) * 8 + (col & 7);
          He[off] = f2bf(gelu_exact(v));
        }
      }
    }
  }
}

// ---------------- GEMM2: yb[slot] = He @ W2f (row-major out; bias+gate in LN) ----------------
__global__ __launch_bounds__(256, 4) void expert_gemm2(
    const unsigned short* __restrict__ He,    // frag, Kd32=64
    const unsigned short* __restrict__ W2f,   // [E] frag, rows=DIM, Kd32=64
    const int* __restrict__ poffs,
    unsigned short* __restrict__ yb) {        // [CAPP][DIM] row-major
  __shared__ __align__(16) unsigned short As[8192], Bs[8192];
  __shared__ int s_po[NE + 1];
  int tid = threadIdx.x, wid = tid >> 6, lane = tid & 63;
  if (tid <= NE) s_po[tid] = poffs[tid];
  __syncthreads();
  int nt = (s_po[NE] >> 7) << 3;              // row-tiles(128) x 8 col-tiles
  int m16 = lane & 15, q = lane >> 4;
  int wr = (wid & 1) << 6, wc = (wid >> 1) << 6;
  int ra = wr >> 4, rc = wc >> 4;
  unsigned short* lA = As + wid * 4 * 512;
  unsigned short* lB = Bs + wid * 4 * 512;
  f32x4_t zero4 = {0.f, 0.f, 0.f, 0.f};
  int bid0 = xcd_swz(blockIdx.x);

  for (int tile = bid0; tile < nt; tile += GEMM_BLOCKS) {
    int rt = tile >> 3, ct = tile & 7;
    int row0 = rt << 7;
    int col0 = ct << 7;
    int e = 0;
    while (e + 1 < NE && s_po[e + 1] <= row0) ++e;
    const unsigned short* Ag = He + ((size_t)((rt << 3) + wid * 2) * 64) * 512 + lane * 8;
    const unsigned short* Bg = W2f + (size_t)e * DIM * HID
                             + ((size_t)((col0 >> 4) + wid * 2) * 64) * 512 + lane * 8;
    f32x4_t acc[4][4];
    #pragma unroll
    for (int i = 0; i < 4; ++i)
      #pragma unroll
      for (int j = 0; j < 4; ++j) acc[i][j] = zero4;

    for (int k0 = 0; k0 < HID; k0 += 64) {
      int kc = (k0 >> 5) * 512;
      load16_lds(Ag + kc,                  lA);
      load16_lds(Ag + kc + 512,            lA + 512);
      load16_lds(Ag + kc + 64 * 512,       lA + 1024);
      load16_lds(Ag + kc + 64 * 512 + 512, lA + 1536);
      load16_lds(Bg + kc,                  lB);
      load16_lds(Bg + kc + 512,            lB + 512);
      load16_lds(Bg + kc + 64 * 512,       lB + 1024);
      load16_lds(Bg + kc + 64 * 512 + 512, lB + 1536);
      __syncthreads();
      #pragma unroll
      for (int ks = 0; ks < 2; ++ks) {
        bf16x8_t a[4], b[4];
        #pragma unroll
        for (int i = 0; i < 4; ++i) {
          a[i] = *(const bf16x8_t*)&As[((ra + i) * 2 + ks) * 512 + lane * 8];
          b[i] = *(const bf16x8_t*)&Bs[((rc + i) * 2 + ks) * 512 + lane * 8];
        }
        #pragma unroll
        for (int i = 0; i < 4; ++i)
          #pragma unroll
          for (int j = 0; j < 4; ++j)
            acc[i][j] = __builtin_amdgcn_mfma_f32_16x16x32_bf16(a[i], b[j], acc[i][j], 0, 0, 0);
      }
      __syncthreads();
    }

    #pragma unroll
    for (int i = 0; i < 4; ++i) {
      #pragma unroll
      for (int rr = 0; rr < 4; ++rr) {
        size_t slot = (size_t)(row0 + wr + i * 16 + q * 4 + rr);
        #pragma unroll
        for (int j = 0; j < 4; ++j) {
          int col = col0 + wc + j * 16 + m16;
          yb[slot * DIM + col] = f2bf(acc[i][j][rr]);
        }
      }
    }
  }
}

// ---------------- gather + gate + bias + residual + LayerNorm (vectorized) ----------------
__global__ __launch_bounds__(256) void ln_kernel(
    const float* __restrict__ x, const unsigned short* __restrict__ yb,
    const int* __restrict__ tok_e, const float* __restrict__ tok_g,
    const int* __restrict__ pair_slot, const float* __restrict__ b2,
    const float* __restrict__ gamma, const float* __restrict__ beta,
    float* __restrict__ out) {
  int n = blockIdx.x, tid = threadIdx.x;
  int e0 = tok_e[2 * n], e1 = tok_e[2 * n + 1];
  float g0 = tok_g[2 * n], g1 = tok_g[2 * n + 1];
  size_t s0 = (size_t)pair_slot[2 * n], s1 = (size_t)pair_slot[2 * n + 1];
  const float* xr = x + (size_t)n * DIM;
  const unsigned short* y0 = yb + s0 * DIM;
  const unsigned short* y1 = yb + s1 * DIM;
  const float* b2e0 = b2 + (size_t)e0 * DIM;
  const float* b2e1 = b2 + (size_t)e1 * DIM;
  int d0 = tid << 2;   // thread owns elements d0..d0+3 (256*4 = 1024)
  float4 xv  = *(const float4*)(xr + d0);
  ushort4 yv0 = *(const ushort4*)(y0 + d0);
  ushort4 yv1 = *(const ushort4*)(y1 + d0);
  float4 bv0 = *(const float4*)(b2e0 + d0);
  float4 bv1 = *(const float4*)(b2e1 + d0);
  float z[4], s = 0.f, s2 = 0.f;
  {
    const float* xp = (const float*)&xv;
    const unsigned short* y0p = (const unsigned short*)&yv0;
    const unsigned short* y1p = (const unsigned short*)&yv1;
    const float* b0p = (const float*)&bv0;
    const float* b1p = (const float*)&bv1;
    #pragma unroll
    for (int jj = 0; jj < 4; ++jj) {
      float v = xp[jj] + g0 * (bf2f(y0p[jj]) + b0p[jj]) + g1 * (bf2f(y1p[jj]) + b1p[jj]);
      z[jj] = v; s += v; s2 += v * v;
    }
  }
  for (int o = 32; o > 0; o >>= 1) { s += __shfl_down(s, o, 64); s2 += __shfl_down(s2, o, 64); }
  __shared__ float rs[4], rs2[4];
  int wid = tid >> 6, lane = tid & 63;
  if (lane == 0) { rs[wid] = s; rs2[wid] = s2; }
  __syncthreads();
  float ts = rs[0] + rs[1] + rs[2] + rs[3];
  float ts2 = rs2[0] + rs2[1] + rs2[2] + rs2[3];
  float mu = ts * (1.f / DIM);
  float var = ts2 * (1.f / DIM) - mu * mu;
  float rstd = rsqrtf(var + 1e-5f);
  float4 gv = *(const float4*)(gamma + d0);
  float4 bv = *(const float4*)(beta + d0);
  float4 ov;
  {
    const float* gp = (const float*)&gv;
    const float* bp = (const float*)&bv;
    float* op = (float*)&ov;
    #pragma unroll
    for (int jj = 0; jj < 4; ++jj)
      op[jj] = (z[jj] - mu) * rstd * gp[jj] + bp[jj];
  }
  *(float4*)(out + (size_t)n * DIM + d0) = ov;
}

extern "C" void kernel_launch(void* const* d_in, const int* in_sizes, int n_in,
                              void* d_out, int out_size, void* d_ws, size_t ws_size,
                              hipStream_t stream) {
  const float* x     = (const float*)d_in[0];
  const float* gW    = (const float*)d_in[1];
  const float* gb    = (const float*)d_in[2];
  const float* W1    = (const float*)d_in[3];
  const float* b1    = (const float*)d_in[4];
  const float* W2    = (const float*)d_in[5];
  const float* b2    = (const float*)d_in[6];
  const float* gamma = (const float*)d_in[7];
  const float* beta  = (const float*)d_in[8];
  float* out = (float*)d_out;

  // workspace layout (~166 MB), all chunks 16B-aligned
  char* w = (char*)d_ws;
  unsigned short* W1f = (unsigned short*)w; w += (size_t)NE * HID * DIM * 2;
  unsigned short* W2f = (unsigned short*)w; w += (size_t)NE * DIM * HID * 2;
  unsigned short* He  = (unsigned short*)w; w += (size_t)CAPP * HID * 2;
  unsigned short* AbY = (unsigned short*)w; w += (size_t)CAPP * DIM * 2;  // Ab1, then yb (aliased)
  int*   row_token    = (int*)w;            w += (size_t)CAPP * 4;
  float* row_gate     = (float*)w;          w += (size_t)CAPP * 4;
  int*   tok_e        = (int*)w;            w += (size_t)NPAIR * 4;
  float* tok_g        = (float*)w;          w += (size_t)NPAIR * 4;
  int*   pair_slot    = (int*)w;            w += (size_t)NPAIR * 4;
  float* imp          = (float*)w;          // 8 floats
  float* ent_sum      = imp + 8;            // 1 float (+7 pad)
  int*   cntp         = (int*)(imp + 16);   // 8 ints
  int*   cursor       = cntp + 8;           // 8 ints
  int*   poffs        = cursor + 8;         // 9 ints

  unsigned short* Ab1 = AbY;                // gemm1 input (dead after gemm1)
  unsigned short* yb  = AbY;                // gemm2 output (written after Ab1 dead)

  hipMemsetAsync(imp, 0, 256, stream);      // imp, ent_sum, cnt

  w_to_frag<DIM, HID><<<dim3(HID / 256, DIM / 32, NE), 256, 0, stream>>>(W1, W1f);
  w_to_frag<HID, DIM><<<dim3(DIM / 256, HID / 32, NE), 256, 0, stream>>>(W2, W2f);
  router_kernel<<<R_BLOCKS, 256, 0, stream>>>(x, gW, gb, tok_e, tok_g, cntp, imp, ent_sum);
  finalize_kernel<<<1, 64, 0, stream>>>(cntp, poffs, cursor, imp, ent_sum, out + TAIL);
  scatter_kernel<<<N_TOK / 256, 256, 0, stream>>>(tok_e, tok_g, cursor, row_token, row_gate, pair_slot);
  gather_a1<<<dim3(4096, 1, NE), 256, 0, stream>>>(x, row_token, cntp, poffs, Ab1);
  expert_gemm1<<<GEMM_BLOCKS, 256, 0, stream>>>(Ab1, W1f, b1, poffs, He);
  expert_gemm2<<<GEMM_BLOCKS, 256, 0, stream>>>(He, W2f, poffs, yb);
  ln_kernel<<<N_TOK, 256, 0, stream>>>(x, yb, tok_e, tok_g, pair_slot, b2, gamma, beta, out);
}

// Round 9
// 484.098 us; speedup vs baseline: 2.1282x; 1.0044x over previous
//
#include <hip/hip_runtime.h>
#include <math.h>

#define N_TOK 8192
#define DIM   1024
#define HID   2048
#define NE    8
#define NPAIR (N_TOK * 2)          // 16384 (token, expert) pairs exactly
#define CAPP  (NPAIR + NE * 128)   // 17408: expert regions padded to 128 rows
#define TAIL  (N_TOK * DIM)        // offset of scalar outputs in d_out

typedef __bf16 bf16x8_t __attribute__((ext_vector_type(8)));
typedef float  f32x4_t  __attribute__((ext_vector_type(4)));

__device__ __forceinline__ unsigned short f2bf(float f) {
  union { float f; unsigned u; } v; v.f = f;
  unsigned r = v.u + 0x7fffu + ((v.u >> 16) & 1u);   // RNE
  return (unsigned short)(r >> 16);
}

__device__ __forceinline__ float bf2f(unsigned short h) {
  union { unsigned u; float f; } v; v.u = ((unsigned)h) << 16;
  return v.f;
}

// Branchless gelu via A&S 7.1.26 erf approx (max |err_erf| = 1.5e-7 -> gelu
// error ~1e-7*|v|, far below bf16 storage rounding). ~12 VALU ops vs libm
// erff's ~30 branchy ops. R13: gemm1 epilogue was VALU-bound on erff
// (VALUBusy 41% > MfmaUtil 26%; 64 gelu/thread/tile ~ 1.5x the MFMA time).
__device__ __forceinline__ float gelu_fast(float v) {
  float x = fabsf(v) * 0.70710678118654752440f;
  float t = __builtin_amdgcn_rcpf(1.f + 0.3275911f * x);
  float p = t * (0.254829592f + t * (-0.284496736f +
            t * (1.421413741f + t * (-1.453152027f + t * 1.061405429f))));
  float erf_pos = 1.f - p * __expf(-x * x);
  float erf_v = copysignf(erf_pos, v);
  return 0.5f * v * (1.f + erf_v);
}

// async global->LDS DMA, 16B/lane; LDS base wave-uniform, HW scatters lane*16.
__device__ __forceinline__ void load16_lds(const void* g, void* l) {
  __builtin_amdgcn_global_load_lds(
      (const __attribute__((address_space(1))) unsigned int*)g,
      (__attribute__((address_space(3))) unsigned int*)l, 16, 0, 0);
}

// =======================================================================
// Fragment-chunk global layout (R4): a matrix [R rows][Kd k] is stored as
// 1KB chunks; chunk c = (r>>4)*(Kd/32) + (k>>5); within a chunk, lane
// l = (k>>3&3)*16 + (r&15) owns 16B = 8 shorts (k&7 fastest). A GEMM tile
// stage is ONE contiguous-1KB global_load_lds per chunk and fragment
// ds_read_b128 is sequential (0 bank conflicts, proven R3).
//
// GEMMs: persistent 1024 blocks (4/CU hard cap: 128 regs/wave, 512-reg
// SIMD file, m69), R4 inner loop (128x128 tile, 4 waves, BK=64, 32KB
// LDS), XCD-bijective swizzle (R9, 479us proven).
//
// R13: (a) gemm1 epilogue gelu -> branchless fast-erf (VALU was the
// busier pipe); (b) router 128 -> 512 blocks (was 0.5 blocks/CU,
// latency-starved); (c) gather_a1 flat chunk grid (8704 worst-case
// blocks vs 32768 with ~24K dead).
// =======================================================================

// ---------------- weights fp32 [z][Kd][R] -> frag-chunk bf16 (coalesced) ----------------
// grid: (RR/256, KD/32, NE); block 256.
template<int KD, int RR>
__global__ __launch_bounds__(256) void w_to_frag(const float* __restrict__ src,
                                                 unsigned short* __restrict__ dst) {
  constexpr int KD32 = KD / 32;
  __shared__ unsigned short L[256][34];   // [r][kk], +2 pad -> 17-bank stride
  int z = blockIdx.z, kblk = blockIdx.y;
  int r0 = blockIdx.x << 8;
  int t = threadIdx.x;
  const float* s = src + (size_t)z * KD * RR + (size_t)(kblk * 32) * RR + r0 + t;
  #pragma unroll
  for (int kk = 0; kk < 32; ++kk)
    L[t][kk] = f2bf(s[(size_t)kk * RR]);   // 256 consecutive floats per kk: 1KB coalesced
  __syncthreads();
  int lane = t & 63, m16 = lane & 15, q = lane >> 4;
  unsigned short* d = dst + (size_t)z * KD * RR;
  #pragma unroll
  for (int p = 0; p < 4; ++p) {
    int ci = p * 4 + (t >> 6);            // chunk-in-block 0..15
    int c = ((r0 >> 4) + ci) * KD32 + kblk;
    uint4 v = *(const uint4*)&L[ci * 16 + m16][q * 8];   // 8 shorts k = q*8..q*8+7
    *(uint4*)(d + (size_t)c * 512 + lane * 8) = v;
  }
}

// ---------------- router: logits (fp32), top-2, softmax, aux stats ----------------
#define R_BLOCKS 512
#define R_TPW    (N_TOK / (R_BLOCKS * 4))   // 4 tokens per wave
__global__ __launch_bounds__(256) void router_kernel(
    const float* __restrict__ x, const float* __restrict__ gW, const float* __restrict__ gb,
    int* __restrict__ tok_e, float* __restrict__ tok_g,
    int* __restrict__ cnt, float* __restrict__ imp, float* __restrict__ ent_sum) {
  __shared__ int s_cnt[NE];
  __shared__ float s_imp[NE];
  __shared__ float s_ent;
  int tid = threadIdx.x;
  if (tid < NE) { s_cnt[tid] = 0; s_imp[tid] = 0.f; }
  if (tid == 0) s_ent = 0.f;
  __syncthreads();
  int wid = tid >> 6, lane = tid & 63;
  int t0 = (blockIdx.x * 4 + wid) * R_TPW;
  float imp_loc[8] = {0.f, 0.f, 0.f, 0.f, 0.f, 0.f, 0.f, 0.f};
  float ent_loc = 0.f;
  for (int t = 0; t < R_TPW; ++t) {
    int n = t0 + t;
    const float* xr = x + (size_t)n * DIM;
    float p[8] = {0.f, 0.f, 0.f, 0.f, 0.f, 0.f, 0.f, 0.f};
    #pragma unroll
    for (int it = 0; it < DIM / 64; ++it) {
      int d = lane + (it << 6);
      float xv = xr[d];
      const float4* g4 = (const float4*)(gW + (size_t)d * NE);
      float4 a = g4[0], b = g4[1];
      p[0] += xv * a.x; p[1] += xv * a.y; p[2] += xv * a.z; p[3] += xv * a.w;
      p[4] += xv * b.x; p[5] += xv * b.y; p[6] += xv * b.z; p[7] += xv * b.w;
    }
    #pragma unroll
    for (int e = 0; e < 8; ++e)
      for (int o = 32; o > 0; o >>= 1) p[e] += __shfl_down(p[e], o, 64);
    if (lane == 0) {
      float lg[8];
      #pragma unroll
      for (int e = 0; e < 8; ++e) lg[e] = p[e] + gb[e];
      int i0 = 0;
      #pragma unroll
      for (int e = 1; e < 8; ++e) if (lg[e] > lg[i0]) i0 = e;   // ties -> lowest idx
      int i1 = (i0 == 0) ? 1 : 0;
      #pragma unroll
      for (int e = 0; e < 8; ++e) if (e != i0 && lg[e] > lg[i1]) i1 = e;
      float d1 = expf(lg[i1] - lg[i0]);
      float g0 = 1.f / (1.f + d1);
      float g1 = d1 * g0;
      tok_e[2 * n] = i0; tok_e[2 * n + 1] = i1;
      tok_g[2 * n] = g0; tok_g[2 * n + 1] = g1;
      atomicAdd(&s_cnt[i0], 1);
      atomicAdd(&s_cnt[i1], 1);
      float mx = lg[i0], s = 0.f, pe[8];
      #pragma unroll
      for (int e = 0; e < 8; ++e) { pe[e] = expf(lg[e] - mx); s += pe[e]; }
      float inv = 1.f / s;
      #pragma unroll
      for (int e = 0; e < 8; ++e) {
        float pr = pe[e] * inv;
        imp_loc[e] += pr;
        ent_loc -= pr * logf(pr + 1e-8f);
      }
    }
  }
  if (lane == 0) {
    #pragma unroll
    for (int e = 0; e < 8; ++e) atomicAdd(&s_imp[e], imp_loc[e]);
    atomicAdd(&s_ent, ent_loc);
  }
  __syncthreads();
  const float invN = 1.f / (float)N_TOK;
  if (tid < NE) {
    atomicAdd(&cnt[tid], s_cnt[tid]);
    atomicAdd(&imp[tid], s_imp[tid] * invN);
  }
  if (tid == NE) atomicAdd(ent_sum, s_ent * invN);
}

// ---------------- finalize: padded offsets/cursors + scalar outputs ----------------
__global__ void finalize_kernel(const int* __restrict__ cnt, int* __restrict__ poffs,
                                int* __restrict__ cursor, const float* __restrict__ imp,
                                const float* __restrict__ ent_sum, float* __restrict__ out_tail) {
  if (threadIdx.x == 0) {
    int off = 0; float bal = 0.f, util = 0.f;
    for (int e = 0; e < NE; ++e) {
      poffs[e] = off; cursor[e] = off;
      off += ((cnt[e] + 127) >> 7) << 7;   // 128-aligned region per expert
      float ld = (float)cnt[e] * (1.f / (float)N_TOK);
      float im = imp[e];
      out_tail[3 + e] = ld;        // load
      out_tail[11 + e] = im;       // importance
      bal += im * ld;
      util -= ld * logf(ld + 1e-8f);
    }
    poffs[NE] = off;
    out_tail[0] = (float)NE * bal; // balance_loss
    out_tail[1] = *ent_sum;        // entropy
    out_tail[2] = util;            // utilization_entropy
  }
}

// ---------------- scatter pairs into (padded) expert buckets ----------------
__global__ __launch_bounds__(256) void scatter_kernel(
    const int* __restrict__ tok_e, const float* __restrict__ tok_g,
    int* __restrict__ cursor, int* __restrict__ row_token, float* __restrict__ row_gate,
    int* __restrict__ pair_slot) {
  __shared__ int s_cnt[NE], s_base[NE], s_rank[NE];
  int tid = threadIdx.x;
  if (tid < NE) { s_cnt[tid] = 0; s_rank[tid] = 0; }
  __syncthreads();
  int n = blockIdx.x * 256 + tid;
  int e0 = tok_e[2 * n], e1 = tok_e[2 * n + 1];
  atomicAdd(&s_cnt[e0], 1);
  atomicAdd(&s_cnt[e1], 1);
  __syncthreads();
  if (tid < NE) s_base[tid] = atomicAdd(&cursor[tid], s_cnt[tid]);
  __syncthreads();
  int r0 = atomicAdd(&s_rank[e0], 1);
  int s0 = s_base[e0] + r0;
  row_token[s0] = n; row_gate[s0] = tok_g[2 * n]; pair_slot[2 * n] = s0;
  int r1 = atomicAdd(&s_rank[e1], 1);
  int s1 = s_base[e1] + r1;
  row_token[s1] = n; row_gate[s1] = tok_g[2 * n + 1]; pair_slot[2 * n + 1] = s1;
}

// ---------------- gather bucketed A (x rows -> frag-chunk bf16, Kd=1024) ----------------
// Flat chunk grid over ALL experts: chunk cl -> slot-block sb=cl>>5, kblk=cl&31;
// expert found via register poffs scan (slot-blocks never cross 128-aligned regions).
#define GA_BLOCKS ((CAPP >> 4) * 32 / 4)   // 8704 worst-case (4 chunks/block)
__global__ __launch_bounds__(256) void gather_a1(
    const float* __restrict__ x, const int* __restrict__ row_token,
    const int* __restrict__ cnt, const int* __restrict__ poffs,
    unsigned short* __restrict__ Ab1) {
  int po[NE + 1];
  #pragma unroll
  for (int i = 0; i <= NE; ++i) po[i] = poffs[i];
  int nch = (po[NE] >> 4) * 32;            // actual total chunks
  int cl = blockIdx.x * 4 + (threadIdx.x >> 6);
  if (cl >= nch) return;                   // wave-uniform exit
  int lane = threadIdx.x & 63, m16 = lane & 15, q = lane >> 4;
  int sb = cl >> 5, kblk = cl & 31;
  int slot = (sb << 4) + m16;
  int e = 0;
  #pragma unroll
  for (int k = 1; k < NE; ++k) e += (po[k] <= slot) ? 1 : 0;   // monotone scan
  int sl = slot - po[e];
  int tok = (sl < cnt[e]) ? row_token[slot] : 0;   // pad rows: token 0 (finite)
  int k = kblk * 32 + q * 8;
  const float4* sp = (const float4*)(x + (size_t)tok * DIM + k);
  float4 v0 = sp[0], v1 = sp[1];
  unsigned short t[8] = {f2bf(v0.x), f2bf(v0.y), f2bf(v0.z), f2bf(v0.w),
                         f2bf(v1.x), f2bf(v1.y), f2bf(v1.z), f2bf(v1.w)};
  *(uint4*)(Ab1 + ((size_t)sb * 32 + kblk) * 512 + lane * 8) = *(uint4*)t;
}

#define GEMM_BLOCKS 1024   // 4 blocks/CU x 256 CU (hard cap: 128 regs/wave, m69)

// XCD-bijective swizzle (T1): 1024 % 8 == 0 so the simple form is bijective.
__device__ __forceinline__ int xcd_swz(int bid) {
  return (bid & 7) * (GEMM_BLOCKS >> 3) + (bid >> 3);
}

// ---------------- GEMM1: He = gelu(Ab1 @ W1f + b1), He in frag order (Kd=2048) ----------------
// Persistent grid; R4 inner loop: 128x128 tile, 4 waves, 64x64/wave, BK=64. (R9-exact)
__global__ __launch_bounds__(256, 4) void expert_gemm1(
    const unsigned short* __restrict__ Ab1,   // frag, Kd32=32
    const unsigned short* __restrict__ W1f,   // [E] frag, rows=HID, Kd32=32
    const float* __restrict__ b1,             // [E][H]
    const int* __restrict__ poffs,
    unsigned short* __restrict__ He) {        // frag, rows=CAPP, Kd32=64
  __shared__ __align__(16) unsigned short As[8192], Bs[8192];
  __shared__ int s_po[NE + 1];
  int tid = threadIdx.x, wid = tid >> 6, lane = tid & 63;
  if (tid <= NE) s_po[tid] = poffs[tid];
  __syncthreads();
  int nt = (s_po[NE] >> 7) << 4;              // row-tiles(128) x 16 col-tiles
  int m16 = lane & 15, q = lane >> 4;
  int wr = (wid & 1) << 6, wc = (wid >> 1) << 6;
  int ra = wr >> 4, rc = wc >> 4;
  unsigned short* lA = As + wid * 4 * 512;
  unsigned short* lB = Bs + wid * 4 * 512;
  f32x4_t zero4 = {0.f, 0.f, 0.f, 0.f};
  int bid0 = xcd_swz(blockIdx.x);

  for (int tile = bid0; tile < nt; tile += GEMM_BLOCKS) {
    int rt = tile >> 4, ct = tile & 15;
    int col0 = ct << 7;
    int row0 = rt << 7;                       // absolute slot row (region-aligned)
    int e = 0;
    while (e + 1 < NE && s_po[e + 1] <= row0) ++e;
    const unsigned short* Ag = Ab1 + ((size_t)((rt << 3) + wid * 2) * 32) * 512 + lane * 8;
    const unsigned short* Bg = W1f + (size_t)e * HID * DIM
                             + ((size_t)((col0 >> 4) + wid * 2) * 32) * 512 + lane * 8;
    f32x4_t acc[4][4];
    #pragma unroll
    for (int i = 0; i < 4; ++i)
      #pragma unroll
      for (int j = 0; j < 4; ++j) acc[i][j] = zero4;

    for (int k0 = 0; k0 < DIM; k0 += 64) {
      int kc = (k0 >> 5) * 512;
      load16_lds(Ag + kc,                  lA);
      load16_lds(Ag + kc + 512,            lA + 512);
      load16_lds(Ag + kc + 32 * 512,       lA + 1024);
      load16_lds(Ag + kc + 32 * 512 + 512, lA + 1536);
      load16_lds(Bg + kc,                  lB);
      load16_lds(Bg + kc + 512,            lB + 512);
      load16_lds(Bg + kc + 32 * 512,       lB + 1024);
      load16_lds(Bg + kc + 32 * 512 + 512, lB + 1536);
      __syncthreads();
      #pragma unroll
      for (int ks = 0; ks < 2; ++ks) {
        bf16x8_t a[4], b[4];
        #pragma unroll
        for (int i = 0; i < 4; ++i) {
          a[i] = *(const bf16x8_t*)&As[((ra + i) * 2 + ks) * 512 + lane * 8];
          b[i] = *(const bf16x8_t*)&Bs[((rc + i) * 2 + ks) * 512 + lane * 8];
        }
        #pragma unroll
        for (int i = 0; i < 4; ++i)
          #pragma unroll
          for (int j = 0; j < 4; ++j)
            acc[i][j] = __builtin_amdgcn_mfma_f32_16x16x32_bf16(a[i], b[j], acc[i][j], 0, 0, 0);
      }
      __syncthreads();
    }

    const float* b1e = b1 + (size_t)e * HID;
    int sb = rt << 3;
    #pragma unroll
    for (int i = 0; i < 4; ++i) {
      size_t sblk = (size_t)(sb + ra + i);
      #pragma unroll
      for (int rr = 0; rr < 4; ++rr) {
        int s15 = q * 4 + rr;   // slot & 15
        #pragma unroll
        for (int j = 0; j < 4; ++j) {
          int col = col0 + wc + j * 16 + m16;
          float v = acc[i][j][rr] + b1e[col];
          size_t off = (sblk * 64 + (col >> 5)) * 512 + (((col >> 3) & 3) * 16 + s15) * 8 + (col & 7);
          He[off] = f2bf(gelu_fast(v));
        }
      }
    }
  }
}

// ---------------- GEMM2: yb[slot] = He @ W2f (row-major out; bias+gate in LN) ----------------
__global__ __launch_bounds__(256, 4) void expert_gemm2(
    const unsigned short* __restrict__ He,    // frag, Kd32=64
    const unsigned short* __restrict__ W2f,   // [E] frag, rows=DIM, Kd32=64
    const int* __restrict__ poffs,
    unsigned short* __restrict__ yb) {        // [CAPP][DIM] row-major
  __shared__ __align__(16) unsigned short As[8192], Bs[8192];
  __shared__ int s_po[NE + 1];
  int tid = threadIdx.x, wid = tid >> 6, lane = tid & 63;
  if (tid <= NE) s_po[tid] = poffs[tid];
  __syncthreads();
  int nt = (s_po[NE] >> 7) << 3;              // row-tiles(128) x 8 col-tiles
  int m16 = lane & 15, q = lane >> 4;
  int wr = (wid & 1) << 6, wc = (wid >> 1) << 6;
  int ra = wr >> 4, rc = wc >> 4;
  unsigned short* lA = As + wid * 4 * 512;
  unsigned short* lB = Bs + wid * 4 * 512;
  f32x4_t zero4 = {0.f, 0.f, 0.f, 0.f};
  int bid0 = xcd_swz(blockIdx.x);

  for (int tile = bid0; tile < nt; tile += GEMM_BLOCKS) {
    int rt = tile >> 3, ct = tile & 7;
    int row0 = rt << 7;
    int col0 = ct << 7;
    int e = 0;
    while (e + 1 < NE && s_po[e + 1] <= row0) ++e;
    const unsigned short* Ag = He + ((size_t)((rt << 3) + wid * 2) * 64) * 512 + lane * 8;
    const unsigned short* Bg = W2f + (size_t)e * DIM * HID
                             + ((size_t)((col0 >> 4) + wid * 2) * 64) * 512 + lane * 8;
    f32x4_t acc[4][4];
    #pragma unroll
    for (int i = 0; i < 4; ++i)
      #pragma unroll
      for (int j = 0; j < 4; ++j) acc[i][j] = zero4;

    for (int k0 = 0; k0 < HID; k0 += 64) {
      int kc = (k0 >> 5) * 512;
      load16_lds(Ag + kc,                  lA);
      load16_lds(Ag + kc + 512,            lA + 512);
      load16_lds(Ag + kc + 64 * 512,       lA + 1024);
      load16_lds(Ag + kc + 64 * 512 + 512, lA + 1536);
      load16_lds(Bg + kc,                  lB);
      load16_lds(Bg + kc + 512,            lB + 512);
      load16_lds(Bg + kc + 64 * 512,       lB + 1024);
      load16_lds(Bg + kc + 64 * 512 + 512, lB + 1536);
      __syncthreads();
      #pragma unroll
      for (int ks = 0; ks < 2; ++ks) {
        bf16x8_t a[4], b[4];
        #pragma unroll
        for (int i = 0; i < 4; ++i) {
          a[i] = *(const bf16x8_t*)&As[((ra + i) * 2 + ks) * 512 + lane * 8];
          b[i] = *(const bf16x8_t*)&Bs[((rc + i) * 2 + ks) * 512 + lane * 8];
        }
        #pragma unroll
        for (int i = 0; i < 4; ++i)
          #pragma unroll
          for (int j = 0; j < 4; ++j)
            acc[i][j] = __builtin_amdgcn_mfma_f32_16x16x32_bf16(a[i], b[j], acc[i][j], 0, 0, 0);
      }
      __syncthreads();
    }

    #pragma unroll
    for (int i = 0; i < 4; ++i) {
      #pragma unroll
      for (int rr = 0; rr < 4; ++rr) {
        size_t slot = (size_t)(row0 + wr + i * 16 + q * 4 + rr);
        #pragma unroll
        for (int j = 0; j < 4; ++j) {
          int col = col0 + wc + j * 16 + m16;
          yb[slot * DIM + col] = f2bf(acc[i][j][rr]);
        }
      }
    }
  }
}

// ---------------- gather + gate + bias + residual + LayerNorm (vectorized) ----------------
__global__ __launch_bounds__(256) void ln_kernel(
    const float* __restrict__ x, const unsigned short* __restrict__ yb,
    const int* __restrict__ tok_e, const float* __restrict__ tok_g,
    const int* __restrict__ pair_slot, const float* __restrict__ b2,
    const float* __restrict__ gamma, const float* __restrict__ beta,
    float* __restrict__ out) {
  int n = blockIdx.x, tid = threadIdx.x;
  int e0 = tok_e[2 * n], e1 = tok_e[2 * n + 1];
  float g0 = tok_g[2 * n], g1 = tok_g[2 * n + 1];
  size_t s0 = (size_t)pair_slot[2 * n], s1 = (size_t)pair_slot[2 * n + 1];
  const float* xr = x + (size_t)n * DIM;
  const unsigned short* y0 = yb + s0 * DIM;
  const unsigned short* y1 = yb + s1 * DIM;
  const float* b2e0 = b2 + (size_t)e0 * DIM;
  const float* b2e1 = b2 + (size_t)e1 * DIM;
  int d0 = tid << 2;   // thread owns elements d0..d0+3 (256*4 = 1024)
  float4 xv  = *(const float4*)(xr + d0);
  ushort4 yv0 = *(const ushort4*)(y0 + d0);
  ushort4 yv1 = *(const ushort4*)(y1 + d0);
  float4 bv0 = *(const float4*)(b2e0 + d0);
  float4 bv1 = *(const float4*)(b2e1 + d0);
  float z[4], s = 0.f, s2 = 0.f;
  {
    const float* xp = (const float*)&xv;
    const unsigned short* y0p = (const unsigned short*)&yv0;
    const unsigned short* y1p = (const unsigned short*)&yv1;
    const float* b0p = (const float*)&bv0;
    const float* b1p = (const float*)&bv1;
    #pragma unroll
    for (int jj = 0; jj < 4; ++jj) {
      float v = xp[jj] + g0 * (bf2f(y0p[jj]) + b0p[jj]) + g1 * (bf2f(y1p[jj]) + b1p[jj]);
      z[jj] = v; s += v; s2 += v * v;
    }
  }
  for (int o = 32; o > 0; o >>= 1) { s += __shfl_down(s, o, 64); s2 += __shfl_down(s2, o, 64); }
  __shared__ float rs[4], rs2[4];
  int wid = tid >> 6, lane = tid & 63;
  if (lane == 0) { rs[wid] = s; rs2[wid] = s2; }
  __syncthreads();
  float ts = rs[0] + rs[1] + rs[2] + rs[3];
  float ts2 = rs2[0] + rs2[1] + rs2[2] + rs2[3];
  float mu = ts * (1.f / DIM);
  float var = ts2 * (1.f / DIM) - mu * mu;
  float rstd = rsqrtf(var + 1e-5f);
  float4 gv = *(const float4*)(gamma + d0);
  float4 bv = *(const float4*)(beta + d0);
  float4 ov;
  {
    const float* gp = (const float*)&gv;
    const float* bp = (const float*)&bv;
    float* op = (float*)&ov;
    #pragma unroll
    for (int jj = 0; jj < 4; ++jj)
      op[jj] = (z[jj] - mu) * rstd * gp[jj] + bp[jj];
  }
  *(float4*)(out + (size_t)n * DIM + d0) = ov;
}

extern "C" void kernel_launch(void* const* d_in, const int* in_sizes, int n_in,
                              void* d_out, int out_size, void* d_ws, size_t ws_size,
                              hipStream_t stream) {
  const float* x     = (const float*)d_in[0];
  const float* gW    = (const float*)d_in[1];
  const float* gb    = (const float*)d_in[2];
  const float* W1    = (const float*)d_in[3];
  const float* b1    = (const float*)d_in[4];
  const float* W2    = (const float*)d_in[5];
  const float* b2    = (const float*)d_in[6];
  const float* gamma = (const float*)d_in[7];
  const float* beta  = (const float*)d_in[8];
  float* out = (float*)d_out;

  // workspace layout (~166 MB), all chunks 16B-aligned
  char* w = (char*)d_ws;
  unsigned short* W1f = (unsigned short*)w; w += (size_t)NE * HID * DIM * 2;
  unsigned short* W2f = (unsigned short*)w; w += (size_t)NE * DIM * HID * 2;
  unsigned short* He  = (unsigned short*)w; w += (size_t)CAPP * HID * 2;
  unsigned short* AbY = (unsigned short*)w; w += (size_t)CAPP * DIM * 2;  // Ab1, then yb (aliased)
  int*   row_token    = (int*)w;            w += (size_t)CAPP * 4;
  float* row_gate     = (float*)w;          w += (size_t)CAPP * 4;
  int*   tok_e        = (int*)w;            w += (size_t)NPAIR * 4;
  float* tok_g        = (float*)w;          w += (size_t)NPAIR * 4;
  int*   pair_slot    = (int*)w;            w += (size_t)NPAIR * 4;
  float* imp          = (float*)w;          // 8 floats
  float* ent_sum      = imp + 8;            // 1 float (+7 pad)
  int*   cntp         = (int*)(imp + 16);   // 8 ints
  int*   cursor       = cntp + 8;           // 8 ints
  int*   poffs        = cursor + 8;         // 9 ints

  unsigned short* Ab1 = AbY;                // gemm1 input (dead after gemm1)
  unsigned short* yb  = AbY;                // gemm2 output (written after Ab1 dead)

  hipMemsetAsync(imp, 0, 256, stream);      // imp, ent_sum, cnt

  w_to_frag<DIM, HID><<<dim3(HID / 256, DIM / 32, NE), 256, 0, stream>>>(W1, W1f);
  w_to_frag<HID, DIM><<<dim3(DIM / 256, HID / 32, NE), 256, 0, stream>>>(W2, W2f);
  router_kernel<<<R_BLOCKS, 256, 0, stream>>>(x, gW, gb, tok_e, tok_g, cntp, imp, ent_sum);
  finalize_kernel<<<1, 64, 0, stream>>>(cntp, poffs, cursor, imp, ent_sum, out + TAIL);
  scatter_kernel<<<N_TOK / 256, 256, 0, stream>>>(tok_e, tok_g, cursor, row_token, row_gate, pair_slot);
  gather_a1<<<GA_BLOCKS, 256, 0, stream>>>(x, row_token, cntp, poffs, Ab1);
  expert_gemm1<<<GEMM_BLOCKS, 256, 0, stream>>>(Ab1, W1f, b1, poffs, He);
  expert_gemm2<<<GEMM_BLOCKS, 256, 0, stream>>>(He, W2f, poffs, yb);
  ln_kernel<<<N_TOK, 256, 0, stream>>>(x, yb, tok_e, tok_g, pair_slot, b2, gamma, beta, out);
}

// Round 10
// 475.986 us; speedup vs baseline: 2.1645x; 1.0170x over previous
//
#include <hip/hip_runtime.h>
#include <math.h>

#define N_TOK 8192
#define DIM   1024
#define HID   2048
#define NE    8
#define NPAIR (N_TOK * 2)          // 16384 (token, expert) pairs exactly
#define CAPP  (NPAIR + NE * 128)   // 17408: expert regions padded to 128 rows
#define TAIL  (N_TOK * DIM)        // offset of scalar outputs in d_out

typedef __bf16 bf16x8_t __attribute__((ext_vector_type(8)));
typedef float  f32x4_t  __attribute__((ext_vector_type(4)));

__device__ __forceinline__ unsigned short f2bf(float f) {
  union { float f; unsigned u; } v; v.f = f;
  unsigned r = v.u + 0x7fffu + ((v.u >> 16) & 1u);   // RNE
  return (unsigned short)(r >> 16);
}

__device__ __forceinline__ float bf2f(unsigned short h) {
  union { unsigned u; float f; } v; v.u = ((unsigned)h) << 16;
  return v.f;
}

// Branchless gelu via A&S 7.1.26 erf approx (max |err_erf| = 1.5e-7 -> gelu
// error ~1e-7*|v|, far below bf16 storage rounding). ~12 VALU ops.
__device__ __forceinline__ float gelu_fast(float v) {
  float x = fabsf(v) * 0.70710678118654752440f;
  float t = __builtin_amdgcn_rcpf(1.f + 0.3275911f * x);
  float p = t * (0.254829592f + t * (-0.284496736f +
            t * (1.421413741f + t * (-1.453152027f + t * 1.061405429f))));
  float erf_pos = 1.f - p * __expf(-x * x);
  float erf_v = copysignf(erf_pos, v);
  return 0.5f * v * (1.f + erf_v);
}

// async global->LDS DMA, 16B/lane; LDS base wave-uniform, HW scatters lane*16.
__device__ __forceinline__ void load16_lds(const void* g, void* l) {
  __builtin_amdgcn_global_load_lds(
      (const __attribute__((address_space(1))) unsigned int*)g,
      (__attribute__((address_space(3))) unsigned int*)l, 16, 0, 0);
}

// =======================================================================
// Fragment-chunk global layout (R4): a matrix [R rows][Kd k] is stored as
// 1KB chunks; chunk c = (r>>4)*(Kd/32) + (k>>5); within a chunk, lane
// l = (k>>3&3)*16 + (r&15) owns 16B = 8 shorts (k&7 fastest).
//
// GEMMs: persistent 1024 blocks (4/CU hard cap: 128 regs/wave, 512-reg
// SIMD file, m69), R4 inner loop (128x128 tile, 4 waves, BK=64, 32KB
// LDS), XCD-bijective swizzle (R9, 479us proven).
//
// R14: R13's A/B showed gemm1's He epilogue is store-pattern-bound:
// identical store ADDRESSES, but removing erff's VALU pacing doubled
// WRITE_SIZE (98->184MB; burst of scattered u16 stores -> partial-line
// L2 evictions -> RMW). Fix the root cause: stage the 32KB output tile
// in the (dead after K-loop) As/Bs LDS in frag-chunk order, then copy
// out as coalesced uint4 (1KB/wave-instr, full lines). gelu_fast kept.
// =======================================================================

// ---------------- weights fp32 [z][Kd][R] -> frag-chunk bf16 (coalesced) ----------------
// grid: (RR/256, KD/32, NE); block 256.
template<int KD, int RR>
__global__ __launch_bounds__(256) void w_to_frag(const float* __restrict__ src,
                                                 unsigned short* __restrict__ dst) {
  constexpr int KD32 = KD / 32;
  __shared__ unsigned short L[256][34];   // [r][kk], +2 pad -> 17-bank stride
  int z = blockIdx.z, kblk = blockIdx.y;
  int r0 = blockIdx.x << 8;
  int t = threadIdx.x;
  const float* s = src + (size_t)z * KD * RR + (size_t)(kblk * 32) * RR + r0 + t;
  #pragma unroll
  for (int kk = 0; kk < 32; ++kk)
    L[t][kk] = f2bf(s[(size_t)kk * RR]);   // 256 consecutive floats per kk: 1KB coalesced
  __syncthreads();
  int lane = t & 63, m16 = lane & 15, q = lane >> 4;
  unsigned short* d = dst + (size_t)z * KD * RR;
  #pragma unroll
  for (int p = 0; p < 4; ++p) {
    int ci = p * 4 + (t >> 6);            // chunk-in-block 0..15
    int c = ((r0 >> 4) + ci) * KD32 + kblk;
    uint4 v = *(const uint4*)&L[ci * 16 + m16][q * 8];   // 8 shorts k = q*8..q*8+7
    *(uint4*)(d + (size_t)c * 512 + lane * 8) = v;
  }
}

// ---------------- router: logits (fp32), top-2, softmax, aux stats ----------------
#define R_BLOCKS 512
#define R_TPW    (N_TOK / (R_BLOCKS * 4))   // 4 tokens per wave
__global__ __launch_bounds__(256) void router_kernel(
    const float* __restrict__ x, const float* __restrict__ gW, const float* __restrict__ gb,
    int* __restrict__ tok_e, float* __restrict__ tok_g,
    int* __restrict__ cnt, float* __restrict__ imp, float* __restrict__ ent_sum) {
  __shared__ int s_cnt[NE];
  __shared__ float s_imp[NE];
  __shared__ float s_ent;
  int tid = threadIdx.x;
  if (tid < NE) { s_cnt[tid] = 0; s_imp[tid] = 0.f; }
  if (tid == 0) s_ent = 0.f;
  __syncthreads();
  int wid = tid >> 6, lane = tid & 63;
  int t0 = (blockIdx.x * 4 + wid) * R_TPW;
  float imp_loc[8] = {0.f, 0.f, 0.f, 0.f, 0.f, 0.f, 0.f, 0.f};
  float ent_loc = 0.f;
  for (int t = 0; t < R_TPW; ++t) {
    int n = t0 + t;
    const float* xr = x + (size_t)n * DIM;
    float p[8] = {0.f, 0.f, 0.f, 0.f, 0.f, 0.f, 0.f, 0.f};
    #pragma unroll
    for (int it = 0; it < DIM / 64; ++it) {
      int d = lane + (it << 6);
      float xv = xr[d];
      const float4* g4 = (const float4*)(gW + (size_t)d * NE);
      float4 a = g4[0], b = g4[1];
      p[0] += xv * a.x; p[1] += xv * a.y; p[2] += xv * a.z; p[3] += xv * a.w;
      p[4] += xv * b.x; p[5] += xv * b.y; p[6] += xv * b.z; p[7] += xv * b.w;
    }
    #pragma unroll
    for (int e = 0; e < 8; ++e)
      for (int o = 32; o > 0; o >>= 1) p[e] += __shfl_down(p[e], o, 64);
    if (lane == 0) {
      float lg[8];
      #pragma unroll
      for (int e = 0; e < 8; ++e) lg[e] = p[e] + gb[e];
      int i0 = 0;
      #pragma unroll
      for (int e = 1; e < 8; ++e) if (lg[e] > lg[i0]) i0 = e;   // ties -> lowest idx
      int i1 = (i0 == 0) ? 1 : 0;
      #pragma unroll
      for (int e = 0; e < 8; ++e) if (e != i0 && lg[e] > lg[i1]) i1 = e;
      float d1 = expf(lg[i1] - lg[i0]);
      float g0 = 1.f / (1.f + d1);
      float g1 = d1 * g0;
      tok_e[2 * n] = i0; tok_e[2 * n + 1] = i1;
      tok_g[2 * n] = g0; tok_g[2 * n + 1] = g1;
      atomicAdd(&s_cnt[i0], 1);
      atomicAdd(&s_cnt[i1], 1);
      float mx = lg[i0], s = 0.f, pe[8];
      #pragma unroll
      for (int e = 0; e < 8; ++e) { pe[e] = expf(lg[e] - mx); s += pe[e]; }
      float inv = 1.f / s;
      #pragma unroll
      for (int e = 0; e < 8; ++e) {
        float pr = pe[e] * inv;
        imp_loc[e] += pr;
        ent_loc -= pr * logf(pr + 1e-8f);
      }
    }
  }
  if (lane == 0) {
    #pragma unroll
    for (int e = 0; e < 8; ++e) atomicAdd(&s_imp[e], imp_loc[e]);
    atomicAdd(&s_ent, ent_loc);
  }
  __syncthreads();
  const float invN = 1.f / (float)N_TOK;
  if (tid < NE) {
    atomicAdd(&cnt[tid], s_cnt[tid]);
    atomicAdd(&imp[tid], s_imp[tid] * invN);
  }
  if (tid == NE) atomicAdd(ent_sum, s_ent * invN);
}

// ---------------- finalize: padded offsets/cursors + scalar outputs ----------------
__global__ void finalize_kernel(const int* __restrict__ cnt, int* __restrict__ poffs,
                                int* __restrict__ cursor, const float* __restrict__ imp,
                                const float* __restrict__ ent_sum, float* __restrict__ out_tail) {
  if (threadIdx.x == 0) {
    int off = 0; float bal = 0.f, util = 0.f;
    for (int e = 0; e < NE; ++e) {
      poffs[e] = off; cursor[e] = off;
      off += ((cnt[e] + 127) >> 7) << 7;   // 128-aligned region per expert
      float ld = (float)cnt[e] * (1.f / (float)N_TOK);
      float im = imp[e];
      out_tail[3 + e] = ld;        // load
      out_tail[11 + e] = im;       // importance
      bal += im * ld;
      util -= ld * logf(ld + 1e-8f);
    }
    poffs[NE] = off;
    out_tail[0] = (float)NE * bal; // balance_loss
    out_tail[1] = *ent_sum;        // entropy
    out_tail[2] = util;            // utilization_entropy
  }
}

// ---------------- scatter pairs into (padded) expert buckets ----------------
__global__ __launch_bounds__(256) void scatter_kernel(
    const int* __restrict__ tok_e, const float* __restrict__ tok_g,
    int* __restrict__ cursor, int* __restrict__ row_token, float* __restrict__ row_gate,
    int* __restrict__ pair_slot) {
  __shared__ int s_cnt[NE], s_base[NE], s_rank[NE];
  int tid = threadIdx.x;
  if (tid < NE) { s_cnt[tid] = 0; s_rank[tid] = 0; }
  __syncthreads();
  int n = blockIdx.x * 256 + tid;
  int e0 = tok_e[2 * n], e1 = tok_e[2 * n + 1];
  atomicAdd(&s_cnt[e0], 1);
  atomicAdd(&s_cnt[e1], 1);
  __syncthreads();
  if (tid < NE) s_base[tid] = atomicAdd(&cursor[tid], s_cnt[tid]);
  __syncthreads();
  int r0 = atomicAdd(&s_rank[e0], 1);
  int s0 = s_base[e0] + r0;
  row_token[s0] = n; row_gate[s0] = tok_g[2 * n]; pair_slot[2 * n] = s0;
  int r1 = atomicAdd(&s_rank[e1], 1);
  int s1 = s_base[e1] + r1;
  row_token[s1] = n; row_gate[s1] = tok_g[2 * n + 1]; pair_slot[2 * n + 1] = s1;
}

// ---------------- gather bucketed A (x rows -> frag-chunk bf16, Kd=1024) ----------------
// Flat chunk grid over ALL experts: chunk cl -> slot-block sb=cl>>5, kblk=cl&31;
// expert found via register poffs scan (slot-blocks never cross 128-aligned regions).
#define GA_BLOCKS ((CAPP >> 4) * 32 / 4)   // 8704 worst-case (4 chunks/block)
__global__ __launch_bounds__(256) void gather_a1(
    const float* __restrict__ x, const int* __restrict__ row_token,
    const int* __restrict__ cnt, const int* __restrict__ poffs,
    unsigned short* __restrict__ Ab1) {
  int po[NE + 1];
  #pragma unroll
  for (int i = 0; i <= NE; ++i) po[i] = poffs[i];
  int nch = (po[NE] >> 4) * 32;            // actual total chunks
  int cl = blockIdx.x * 4 + (threadIdx.x >> 6);
  if (cl >= nch) return;                   // wave-uniform exit
  int lane = threadIdx.x & 63, m16 = lane & 15, q = lane >> 4;
  int sb = cl >> 5, kblk = cl & 31;
  int slot = (sb << 4) + m16;
  int e = 0;
  #pragma unroll
  for (int k = 1; k < NE; ++k) e += (po[k] <= slot) ? 1 : 0;   // monotone scan
  int sl = slot - po[e];
  int tok = (sl < cnt[e]) ? row_token[slot] : 0;   // pad rows: token 0 (finite)
  int k = kblk * 32 + q * 8;
  const float4* sp = (const float4*)(x + (size_t)tok * DIM + k);
  float4 v0 = sp[0], v1 = sp[1];
  unsigned short t[8] = {f2bf(v0.x), f2bf(v0.y), f2bf(v0.z), f2bf(v0.w),
                         f2bf(v1.x), f2bf(v1.y), f2bf(v1.z), f2bf(v1.w)};
  *(uint4*)(Ab1 + ((size_t)sb * 32 + kblk) * 512 + lane * 8) = *(uint4*)t;
}

#define GEMM_BLOCKS 1024   // 4 blocks/CU x 256 CU (hard cap: 128 regs/wave, m69)

// XCD-bijective swizzle (T1): 1024 % 8 == 0 so the simple form is bijective.
__device__ __forceinline__ int xcd_swz(int bid) {
  return (bid & 7) * (GEMM_BLOCKS >> 3) + (bid >> 3);
}

// ---------------- GEMM1: He = gelu(Ab1 @ W1f + b1), He in frag order (Kd=2048) ----------------
// Persistent grid; R4 inner loop: 128x128 tile, 4 waves, 64x64/wave, BK=64.
// R14: staged epilogue -- output tile in SMEM (As/Bs overlay, dead after
// K-loop), then coalesced uint4 copy-out (full cachelines, no RMW).
__global__ __launch_bounds__(256, 4) void expert_gemm1(
    const unsigned short* __restrict__ Ab1,   // frag, Kd32=32
    const unsigned short* __restrict__ W1f,   // [E] frag, rows=HID, Kd32=32
    const float* __restrict__ b1,             // [E][H]
    const int* __restrict__ poffs,
    unsigned short* __restrict__ He) {        // frag, rows=CAPP, Kd32=64
  __shared__ __align__(16) unsigned short SMEM[16384];   // As(8192) | Bs(8192); epilogue overlay
  __shared__ int s_po[NE + 1];
  unsigned short* As = SMEM;
  unsigned short* Bs = SMEM + 8192;
  int tid = threadIdx.x, wid = tid >> 6, lane = tid & 63;
  if (tid <= NE) s_po[tid] = poffs[tid];
  __syncthreads();
  int nt = (s_po[NE] >> 7) << 4;              // row-tiles(128) x 16 col-tiles
  int m16 = lane & 15, q = lane >> 4;
  int wr = (wid & 1) << 6, wc = (wid >> 1) << 6;
  int ra = wr >> 4, rc = wc >> 4;
  unsigned short* lA = As + wid * 4 * 512;
  unsigned short* lB = Bs + wid * 4 * 512;
  f32x4_t zero4 = {0.f, 0.f, 0.f, 0.f};
  int bid0 = xcd_swz(blockIdx.x);

  for (int tile = bid0; tile < nt; tile += GEMM_BLOCKS) {
    int rt = tile >> 4, ct = tile & 15;
    int col0 = ct << 7;
    int row0 = rt << 7;                       // absolute slot row (region-aligned)
    int e = 0;
    while (e + 1 < NE && s_po[e + 1] <= row0) ++e;
    const unsigned short* Ag = Ab1 + ((size_t)((rt << 3) + wid * 2) * 32) * 512 + lane * 8;
    const unsigned short* Bg = W1f + (size_t)e * HID * DIM
                             + ((size_t)((col0 >> 4) + wid * 2) * 32) * 512 + lane * 8;
    f32x4_t acc[4][4];
    #pragma unroll
    for (int i = 0; i < 4; ++i)
      #pragma unroll
      for (int j = 0; j < 4; ++j) acc[i][j] = zero4;

    for (int k0 = 0; k0 < DIM; k0 += 64) {
      int kc = (k0 >> 5) * 512;
      load16_lds(Ag + kc,                  lA);
      load16_lds(Ag + kc + 512,            lA + 512);
      load16_lds(Ag + kc + 32 * 512,       lA + 1024);
      load16_lds(Ag + kc + 32 * 512 + 512, lA + 1536);
      load16_lds(Bg + kc,                  lB);
      load16_lds(Bg + kc + 512,            lB + 512);
      load16_lds(Bg + kc + 32 * 512,       lB + 1024);
      load16_lds(Bg + kc + 32 * 512 + 512, lB + 1536);
      __syncthreads();
      #pragma unroll
      for (int ks = 0; ks < 2; ++ks) {
        bf16x8_t a[4], b[4];
        #pragma unroll
        for (int i = 0; i < 4; ++i) {
          a[i] = *(const bf16x8_t*)&As[((ra + i) * 2 + ks) * 512 + lane * 8];
          b[i] = *(const bf16x8_t*)&Bs[((rc + i) * 2 + ks) * 512 + lane * 8];
        }
        #pragma unroll
        for (int i = 0; i < 4; ++i)
          #pragma unroll
          for (int j = 0; j < 4; ++j)
            acc[i][j] = __builtin_amdgcn_mfma_f32_16x16x32_bf16(a[i], b[j], acc[i][j], 0, 0, 0);
      }
      __syncthreads();
    }

    // ---- staged epilogue: write tile into SMEM in frag-chunk order ----
    const float* b1e = b1 + (size_t)e * HID;
    int sb = rt << 3;
    #pragma unroll
    for (int i = 0; i < 4; ++i) {
      #pragma unroll
      for (int rr = 0; rr < 4; ++rr) {
        int s15 = q * 4 + rr;
        #pragma unroll
        for (int j = 0; j < 4; ++j) {
          int r7 = wc + j * 16 + m16;                 // col within tile, 0..127
          float v = acc[i][j][rr] + b1e[col0 + r7];
          int loff = ((ra + i) * 4 + (r7 >> 5)) * 512
                   + (((r7 >> 3) & 3) * 16 + s15) * 8 + (r7 & 7);
          SMEM[loff] = f2bf(gelu_fast(v));
        }
      }
    }
    __syncthreads();
    // ---- coalesced copy-out: 2048 x uint4 (1KB per wave-instruction) ----
    {
      int cb0 = col0 >> 5;
      const uint4* Sv = (const uint4*)SMEM;
      #pragma unroll
      for (int k = 0; k < 8; ++k) {
        int u = tid + (k << 8);
        int lsb = u >> 8;                             // = k
        int lcb = (u >> 6) & 3;
        int p = u & 63;
        size_t goff = ((size_t)(sb + lsb) * 64 + cb0 + lcb) * 512 + p * 8;
        *(uint4*)(He + goff) = Sv[u];
      }
    }
    __syncthreads();   // protect SMEM before next tile's staging
  }
}

// ---------------- GEMM2: yb[slot] = He @ W2f (row-major out; bias+gate in LN) ----------------
__global__ __launch_bounds__(256, 4) void expert_gemm2(
    const unsigned short* __restrict__ He,    // frag, Kd32=64
    const unsigned short* __restrict__ W2f,   // [E] frag, rows=DIM, Kd32=64
    const int* __restrict__ poffs,
    unsigned short* __restrict__ yb) {        // [CAPP][DIM] row-major
  __shared__ __align__(16) unsigned short As[8192], Bs[8192];
  __shared__ int s_po[NE + 1];
  int tid = threadIdx.x, wid = tid >> 6, lane = tid & 63;
  if (tid <= NE) s_po[tid] = poffs[tid];
  __syncthreads();
  int nt = (s_po[NE] >> 7) << 3;              // row-tiles(128) x 8 col-tiles
  int m16 = lane & 15, q = lane >> 4;
  int wr = (wid & 1) << 6, wc = (wid >> 1) << 6;
  int ra = wr >> 4, rc = wc >> 4;
  unsigned short* lA = As + wid * 4 * 512;
  unsigned short* lB = Bs + wid * 4 * 512;
  f32x4_t zero4 = {0.f, 0.f, 0.f, 0.f};
  int bid0 = xcd_swz(blockIdx.x);

  for (int tile = bid0; tile < nt; tile += GEMM_BLOCKS) {
    int rt = tile >> 3, ct = tile & 7;
    int row0 = rt << 7;
    int col0 = ct << 7;
    int e = 0;
    while (e + 1 < NE && s_po[e + 1] <= row0) ++e;
    const unsigned short* Ag = He + ((size_t)((rt << 3) + wid * 2) * 64) * 512 + lane * 8;
    const unsigned short* Bg = W2f + (size_t)e * DIM * HID
                             + ((size_t)((col0 >> 4) + wid * 2) * 64) * 512 + lane * 8;
    f32x4_t acc[4][4];
    #pragma unroll
    for (int i = 0; i < 4; ++i)
      #pragma unroll
      for (int j = 0; j < 4; ++j) acc[i][j] = zero4;

    for (int k0 = 0; k0 < HID; k0 += 64) {
      int kc = (k0 >> 5) * 512;
      load16_lds(Ag + kc,                  lA);
      load16_lds(Ag + kc + 512,            lA + 512);
      load16_lds(Ag + kc + 64 * 512,       lA + 1024);
      load16_lds(Ag + kc + 64 * 512 + 512, lA + 1536);
      load16_lds(Bg + kc,                  lB);
      load16_lds(Bg + kc + 512,            lB + 512);
      load16_lds(Bg + kc + 64 * 512,       lB + 1024);
      load16_lds(Bg + kc + 64 * 512 + 512, lB + 1536);
      __syncthreads();
      #pragma unroll
      for (int ks = 0; ks < 2; ++ks) {
        bf16x8_t a[4], b[4];
        #pragma unroll
        for (int i = 0; i < 4; ++i) {
          a[i] = *(const bf16x8_t*)&As[((ra + i) * 2 + ks) * 512 + lane * 8];
          b[i] = *(const bf16x8_t*)&Bs[((rc + i) * 2 + ks) * 512 + lane * 8];
        }
        #pragma unroll
        for (int i = 0; i < 4; ++i)
          #pragma unroll
          for (int j = 0; j < 4; ++j)
            acc[i][j] = __builtin_amdgcn_mfma_f32_16x16x32_bf16(a[i], b[j], acc[i][j], 0, 0, 0);
      }
      __syncthreads();
    }

    #pragma unroll
    for (int i = 0; i < 4; ++i) {
      #pragma unroll
      for (int rr = 0; rr < 4; ++rr) {
        size_t slot = (size_t)(row0 + wr + i * 16 + q * 4 + rr);
        #pragma unroll
        for (int j = 0; j < 4; ++j) {
          int col = col0 + wc + j * 16 + m16;
          yb[slot * DIM + col] = f2bf(acc[i][j][rr]);
        }
      }
    }
  }
}

// ---------------- gather + gate + bias + residual + LayerNorm (vectorized) ----------------
__global__ __launch_bounds__(256) void ln_kernel(
    const float* __restrict__ x, const unsigned short* __restrict__ yb,
    const int* __restrict__ tok_e, const float* __restrict__ tok_g,
    const int* __restrict__ pair_slot, const float* __restrict__ b2,
    const float* __restrict__ gamma, const float* __restrict__ beta,
    float* __restrict__ out) {
  int n = blockIdx.x, tid = threadIdx.x;
  int e0 = tok_e[2 * n], e1 = tok_e[2 * n + 1];
  float g0 = tok_g[2 * n], g1 = tok_g[2 * n + 1];
  size_t s0 = (size_t)pair_slot[2 * n], s1 = (size_t)pair_slot[2 * n + 1];
  const float* xr = x + (size_t)n * DIM;
  const unsigned short* y0 = yb + s0 * DIM;
  const unsigned short* y1 = yb + s1 * DIM;
  const float* b2e0 = b2 + (size_t)e0 * DIM;
  const float* b2e1 = b2 + (size_t)e1 * DIM;
  int d0 = tid << 2;   // thread owns elements d0..d0+3 (256*4 = 1024)
  float4 xv  = *(const float4*)(xr + d0);
  ushort4 yv0 = *(const ushort4*)(y0 + d0);
  ushort4 yv1 = *(const ushort4*)(y1 + d0);
  float4 bv0 = *(const float4*)(b2e0 + d0);
  float4 bv1 = *(const float4*)(b2e1 + d0);
  float z[4], s = 0.f, s2 = 0.f;
  {
    const float* xp = (const float*)&xv;
    const unsigned short* y0p = (const unsigned short*)&yv0;
    const unsigned short* y1p = (const unsigned short*)&yv1;
    const float* b0p = (const float*)&bv0;
    const float* b1p = (const float*)&bv1;
    #pragma unroll
    for (int jj = 0; jj < 4; ++jj) {
      float v = xp[jj] + g0 * (bf2f(y0p[jj]) + b0p[jj]) + g1 * (bf2f(y1p[jj]) + b1p[jj]);
      z[jj] = v; s += v; s2 += v * v;
    }
  }
  for (int o = 32; o > 0; o >>= 1) { s += __shfl_down(s, o, 64); s2 += __shfl_down(s2, o, 64); }
  __shared__ float rs[4], rs2[4];
  int wid = tid >> 6, lane = tid & 63;
  if (lane == 0) { rs[wid] = s; rs2[wid] = s2; }
  __syncthreads();
  float ts = rs[0] + rs[1] + rs[2] + rs[3];
  float ts2 = rs2[0] + rs2[1] + rs2[2] + rs2[3];
  float mu = ts * (1.f / DIM);
  float var = ts2 * (1.f / DIM) - mu * mu;
  float rstd = rsqrtf(var + 1e-5f);
  float4 gv = *(const float4*)(gamma + d0);
  float4 bv = *(const float4*)(beta + d0);
  float4 ov;
  {
    const float* gp = (const float*)&gv;
    const float* bp = (const float*)&bv;
    float* op = (float*)&ov;
    #pragma unroll
    for (int jj = 0; jj < 4; ++jj)
      op[jj] = (z[jj] - mu) * rstd * gp[jj] + bp[jj];
  }
  *(float4*)(out + (size_t)n * DIM + d0) = ov;
}

extern "C" void kernel_launch(void* const* d_in, const int* in_sizes, int n_in,
                              void* d_out, int out_size, void* d_ws, size_t ws_size,
                              hipStream_t stream) {
  const float* x     = (const float*)d_in[0];
  const float* gW    = (const float*)d_in[1];
  const float* gb    = (const float*)d_in[2];
  const float* W1    = (const float*)d_in[3];
  const float* b1    = (const float*)d_in[4];
  const float* W2    = (const float*)d_in[5];
  const float* b2    = (const float*)d_in[6];
  const float* gamma = (const float*)d_in[7];
  const float* beta  = (const float*)d_in[8];
  float* out = (float*)d_out;

  // workspace layout (~166 MB), all chunks 16B-aligned
  char* w = (char*)d_ws;
  unsigned short* W1f = (unsigned short*)w; w += (size_t)NE * HID * DIM * 2;
  unsigned short* W2f = (unsigned short*)w; w += (size_t)NE * DIM * HID * 2;
  unsigned short* He  = (unsigned short*)w; w += (size_t)CAPP * HID * 2;
  unsigned short* AbY = (unsigned short*)w; w += (size_t)CAPP * DIM * 2;  // Ab1, then yb (aliased)
  int*   row_token    = (int*)w;            w += (size_t)CAPP * 4;
  float* row_gate     = (float*)w;          w += (size_t)CAPP * 4;
  int*   tok_e        = (int*)w;            w += (size_t)NPAIR * 4;
  float* tok_g        = (float*)w;          w += (size_t)NPAIR * 4;
  int*   pair_slot    = (int*)w;            w += (size_t)NPAIR * 4;
  float* imp          = (float*)w;          // 8 floats
  float* ent_sum      = imp + 8;            // 1 float (+7 pad)
  int*   cntp         = (int*)(imp + 16);   // 8 ints
  int*   cursor       = cntp + 8;           // 8 ints
  int*   poffs        = cursor + 8;         // 9 ints

  unsigned short* Ab1 = AbY;                // gemm1 input (dead after gemm1)
  unsigned short* yb  = AbY;                // gemm2 output (written after Ab1 dead)

  hipMemsetAsync(imp, 0, 256, stream);      // imp, ent_sum, cnt

  w_to_frag<DIM, HID><<<dim3(HID / 256, DIM / 32, NE), 256, 0, stream>>>(W1, W1f);
  w_to_frag<HID, DIM><<<dim3(DIM / 256, HID / 32, NE), 256, 0, stream>>>(W2, W2f);
  router_kernel<<<R_BLOCKS, 256, 0, stream>>>(x, gW, gb, tok_e, tok_g, cntp, imp, ent_sum);
  finalize_kernel<<<1, 64, 0, stream>>>(cntp, poffs, cursor, imp, ent_sum, out + TAIL);
  scatter_kernel<<<N_TOK / 256, 256, 0, stream>>>(tok_e, tok_g, cursor, row_token, row_gate, pair_slot);
  gather_a1<<<GA_BLOCKS, 256, 0, stream>>>(x, row_token, cntp, poffs, Ab1);
  expert_gemm1<<<GEMM_BLOCKS, 256, 0, stream>>>(Ab1, W1f, b1, poffs, He);
  expert_gemm2<<<GEMM_BLOCKS, 256, 0, stream>>>(He, W2f, poffs, yb);
  ln_kernel<<<N_TOK, 256, 0, stream>>>(x, yb, tok_e, tok_g, pair_slot, b2, gamma, beta, out);
}

// Round 12
// 451.613 us; speedup vs baseline: 2.2813x; 1.0540x over previous
//
#include <hip/hip_runtime.h>
#include <math.h>

#define N_TOK 8192
#define DIM   1024
#define HID   2048
#define NE    8
#define NPAIR (N_TOK * 2)          // 16384 (token, expert) pairs exactly
#define CAPP  (NPAIR + NE * 128)   // 17408: expert regions padded to 128 rows
#define TAIL  (N_TOK * DIM)        // offset of scalar outputs in d_out

typedef __bf16 bf16x8_t __attribute__((ext_vector_type(8)));
typedef float  f32x4_t  __attribute__((ext_vector_type(4)));

__device__ __forceinline__ unsigned short f2bf(float f) {
  union { float f; unsigned u; } v; v.f = f;
  unsigned r = v.u + 0x7fffu + ((v.u >> 16) & 1u);   // RNE
  return (unsigned short)(r >> 16);
}

__device__ __forceinline__ float bf2f(unsigned short h) {
  union { unsigned u; float f; } v; v.u = ((unsigned)h) << 16;
  return v.f;
}

// erff kept in gemm1 (measured ladder: direct+erff=112us < staged+fast=124
// < direct+fast=152). The libm erff's VALU pacing lets direct u16 stores
// drain under the next tile's K-loop without RMW bursts.
__device__ __forceinline__ float gelu_exact(float v) {
  return 0.5f * v * (1.f + erff(v * 0.70710678118654752440f));
}

// async global->LDS DMA, 16B/lane; LDS base wave-uniform, HW scatters lane*16.
__device__ __forceinline__ void load16_lds(const void* g, void* l) {
  __builtin_amdgcn_global_load_lds(
      (const __attribute__((address_space(1))) unsigned int*)g,
      (__attribute__((address_space(3))) unsigned int*)l, 16, 0, 0);
}

// =======================================================================
// Fragment-chunk global layout (R4): a matrix [R rows][Kd k] is stored as
// 1KB chunks; chunk c = (r>>4)*(Kd/32) + (k>>5); within a chunk, lane
// l = (k>>3&3)*16 + (r&15) owns 16B = 8 shorts (k&7 fastest).
//
// GEMMs: persistent 1024 blocks (4/CU hard cap: 128 regs/wave, 512-reg
// SIMD file, m69), R4 inner loop (128x128 tile, 4 waves, BK=64, 32KB
// LDS), XCD-bijective swizzle; gemm1 = R12's direct-store+erff form
// (fastest measured: 112us).
//
// R15/R16: launch-count cut (modeled kernel time ~360us vs 476 measured
// -> ~100us of enqueue/gap overhead). 10 enqueues -> 7: (a) both
// w_to_frag instantiations merged into one flat-grid launch, which also
// zeroes the stats region (replaces hipMemsetAsync; stream order
// guarantees it precedes router); (b) finalize_kernel deleted --
// scatter computes poffs block-locally from cnt (deterministic prefix
// sum), cursor is zero-based, block 0 writes poffs + scalar outputs.
// R16 = R15 resubmitted: the R15 bench died with "container failed
// twice" (infra, no counters); kernel audit found no OOB/deadlock.
// =======================================================================

// ---------------- weights fp32 [z][Kd][R] -> frag-chunk bf16 (coalesced) ----------------
template<int KD, int RR>
__device__ __forceinline__ void w2f_body(const float* __restrict__ src,
                                         unsigned short* __restrict__ dst,
                                         int bx, int kblk, int z,
                                         unsigned short (*L)[34], int t) {
  constexpr int KD32 = KD / 32;
  int r0 = bx << 8;
  const float* s = src + (size_t)z * KD * RR + (size_t)(kblk * 32) * RR + r0 + t;
  #pragma unroll
  for (int kk = 0; kk < 32; ++kk)
    L[t][kk] = f2bf(s[(size_t)kk * RR]);   // 256 consecutive floats per kk: 1KB coalesced
  __syncthreads();
  int lane = t & 63, m16 = lane & 15, q = lane >> 4;
  unsigned short* d = dst + (size_t)z * KD * RR;
  #pragma unroll
  for (int p = 0; p < 4; ++p) {
    int ci = p * 4 + (t >> 6);            // chunk-in-block 0..15
    int c = ((r0 >> 4) + ci) * KD32 + kblk;
    uint4 v = *(const uint4*)&L[ci * 16 + m16][q * 8];   // 8 shorts k = q*8..q*8+7
    *(uint4*)(d + (size_t)c * 512 + lane * 8) = v;
  }
}

// Merged: flat grid 4096 blocks. [0,2048): W1 (8 x 32 x NE); [2048,4096): W2 (4 x 64 x NE).
// Block 0 also zeroes the 256B stats region (imp/ent/cnt/cursor) before router runs.
__global__ __launch_bounds__(256) void w_to_frag_all(
    const float* __restrict__ W1, const float* __restrict__ W2,
    unsigned short* __restrict__ W1f, unsigned short* __restrict__ W2f,
    float* __restrict__ stats) {
  __shared__ unsigned short L[256][34];   // [r][kk], +2 pad -> 17-bank stride
  int t = threadIdx.x;
  int f = blockIdx.x;
  if (f == 0 && t < 64) stats[t] = 0.f;   // 256B: imp, ent_sum, cnt, cursor
  if (f < 2048) {
    int z = f >> 8, r = f & 255;
    w2f_body<DIM, HID>(W1, W1f, r & 7, r >> 3, z, L, t);
  } else {
    int f2 = f - 2048;
    int z = f2 >> 8, r = f2 & 255;
    w2f_body<HID, DIM>(W2, W2f, r & 3, r >> 2, z, L, t);
  }
}

// ---------------- router: logits (fp32), top-2, softmax, aux stats ----------------
#define R_BLOCKS 512
#define R_TPW    (N_TOK / (R_BLOCKS * 4))   // 4 tokens per wave
__global__ __launch_bounds__(256) void router_kernel(
    const float* __restrict__ x, const float* __restrict__ gW, const float* __restrict__ gb,
    int* __restrict__ tok_e, float* __restrict__ tok_g,
    int* __restrict__ cnt, float* __restrict__ imp, float* __restrict__ ent_sum) {
  __shared__ int s_cnt[NE];
  __shared__ float s_imp[NE];
  __shared__ float s_ent;
  int tid = threadIdx.x;
  if (tid < NE) { s_cnt[tid] = 0; s_imp[tid] = 0.f; }
  if (tid == 0) s_ent = 0.f;
  __syncthreads();
  int wid = tid >> 6, lane = tid & 63;
  int t0 = (blockIdx.x * 4 + wid) * R_TPW;
  float imp_loc[8] = {0.f, 0.f, 0.f, 0.f, 0.f, 0.f, 0.f, 0.f};
  float ent_loc = 0.f;
  for (int t = 0; t < R_TPW; ++t) {
    int n = t0 + t;
    const float* xr = x + (size_t)n * DIM;
    float p[8] = {0.f, 0.f, 0.f, 0.f, 0.f, 0.f, 0.f, 0.f};
    #pragma unroll
    for (int it = 0; it < DIM / 64; ++it) {
      int d = lane + (it << 6);
      float xv = xr[d];
      const float4* g4 = (const float4*)(gW + (size_t)d * NE);
      float4 a = g4[0], b = g4[1];
      p[0] += xv * a.x; p[1] += xv * a.y; p[2] += xv * a.z; p[3] += xv * a.w;
      p[4] += xv * b.x; p[5] += xv * b.y; p[6] += xv * b.z; p[7] += xv * b.w;
    }
    #pragma unroll
    for (int e = 0; e < 8; ++e)
      for (int o = 32; o > 0; o >>= 1) p[e] += __shfl_down(p[e], o, 64);
    if (lane == 0) {
      float lg[8];
      #pragma unroll
      for (int e = 0; e < 8; ++e) lg[e] = p[e] + gb[e];
      int i0 = 0;
      #pragma unroll
      for (int e = 1; e < 8; ++e) if (lg[e] > lg[i0]) i0 = e;   // ties -> lowest idx
      int i1 = (i0 == 0) ? 1 : 0;
      #pragma unroll
      for (int e = 0; e < 8; ++e) if (e != i0 && lg[e] > lg[i1]) i1 = e;
      float d1 = expf(lg[i1] - lg[i0]);
      float g0 = 1.f / (1.f + d1);
      float g1 = d1 * g0;
      tok_e[2 * n] = i0; tok_e[2 * n + 1] = i1;
      tok_g[2 * n] = g0; tok_g[2 * n + 1] = g1;
      atomicAdd(&s_cnt[i0], 1);
      atomicAdd(&s_cnt[i1], 1);
      float mx = lg[i0], s = 0.f, pe[8];
      #pragma unroll
      for (int e = 0; e < 8; ++e) { pe[e] = expf(lg[e] - mx); s += pe[e]; }
      float inv = 1.f / s;
      #pragma unroll
      for (int e = 0; e < 8; ++e) {
        float pr = pe[e] * inv;
        imp_loc[e] += pr;
        ent_loc -= pr * logf(pr + 1e-8f);
      }
    }
  }
  if (lane == 0) {
    #pragma unroll
    for (int e = 0; e < 8; ++e) atomicAdd(&s_imp[e], imp_loc[e]);
    atomicAdd(&s_ent, ent_loc);
  }
  __syncthreads();
  const float invN = 1.f / (float)N_TOK;
  if (tid < NE) {
    atomicAdd(&cnt[tid], s_cnt[tid]);
    atomicAdd(&imp[tid], s_imp[tid] * invN);
  }
  if (tid == NE) atomicAdd(ent_sum, s_ent * invN);
}

// ---------------- scatter pairs + absorbed finalize duties ----------------
// cursor is zero-based (zeroed by w_to_frag_all); poffs computed block-locally
// from cnt (deterministic). Block 0 tid 0 writes global poffs + scalar outputs.
__global__ __launch_bounds__(256) void scatter_kernel(
    const int* __restrict__ tok_e, const float* __restrict__ tok_g,
    const int* __restrict__ cnt, const float* __restrict__ imp,
    const float* __restrict__ ent_sum,
    int* __restrict__ cursor, int* __restrict__ poffs_g, float* __restrict__ out_tail,
    int* __restrict__ row_token, float* __restrict__ row_gate,
    int* __restrict__ pair_slot) {
  __shared__ int s_cnt[NE], s_base[NE], s_rank[NE];
  int tid = threadIdx.x;
  if (tid < NE) { s_cnt[tid] = 0; s_rank[tid] = 0; }
  __syncthreads();
  int n = blockIdx.x * 256 + tid;
  int e0 = tok_e[2 * n], e1 = tok_e[2 * n + 1];
  atomicAdd(&s_cnt[e0], 1);
  atomicAdd(&s_cnt[e1], 1);
  __syncthreads();
  if (tid < NE) {
    int po = 0;
    for (int e = 0; e < tid; ++e) po += ((cnt[e] + 127) >> 7) << 7;   // local prefix
    s_base[tid] = po + atomicAdd(&cursor[tid], s_cnt[tid]);
  }
  __syncthreads();
  int r0 = atomicAdd(&s_rank[e0], 1);
  int s0 = s_base[e0] + r0;
  row_token[s0] = n; row_gate[s0] = tok_g[2 * n]; pair_slot[2 * n] = s0;
  int r1 = atomicAdd(&s_rank[e1], 1);
  int s1 = s_base[e1] + r1;
  row_token[s1] = n; row_gate[s1] = tok_g[2 * n + 1]; pair_slot[2 * n + 1] = s1;
  if (blockIdx.x == 0 && tid == 0) {
    int off = 0; float bal = 0.f, util = 0.f;
    for (int e = 0; e < NE; ++e) {
      poffs_g[e] = off;
      off += ((cnt[e] + 127) >> 7) << 7;
      float ld = (float)cnt[e] * (1.f / (float)N_TOK);
      float im = imp[e];
      out_tail[3 + e] = ld;        // load
      out_tail[11 + e] = im;       // importance
      bal += im * ld;
      util -= ld * logf(ld + 1e-8f);
    }
    poffs_g[NE] = off;
    out_tail[0] = (float)NE * bal; // balance_loss
    out_tail[1] = *ent_sum;        // entropy
    out_tail[2] = util;            // utilization_entropy
  }
}

// ---------------- gather bucketed A (x rows -> frag-chunk bf16, Kd=1024) ----------------
#define GA_BLOCKS ((CAPP >> 4) * 32 / 4)   // 8704 worst-case (4 chunks/block)
__global__ __launch_bounds__(256) void gather_a1(
    const float* __restrict__ x, const int* __restrict__ row_token,
    const int* __restrict__ cnt, const int* __restrict__ poffs,
    unsigned short* __restrict__ Ab1) {
  int po[NE + 1];
  #pragma unroll
  for (int i = 0; i <= NE; ++i) po[i] = poffs[i];
  int nch = (po[NE] >> 4) * 32;            // actual total chunks
  int cl = blockIdx.x * 4 + (threadIdx.x >> 6);
  if (cl >= nch) return;                   // wave-uniform exit
  int lane = threadIdx.x & 63, m16 = lane & 15, q = lane >> 4;
  int sb = cl >> 5, kblk = cl & 31;
  int slot = (sb << 4) + m16;
  int e = 0;
  #pragma unroll
  for (int k = 1; k < NE; ++k) e += (po[k] <= slot) ? 1 : 0;   // monotone scan
  int sl = slot - po[e];
  int tok = (sl < cnt[e]) ? row_token[slot] : 0;   // pad rows: token 0 (finite)
  int k = kblk * 32 + q * 8;
  const float4* sp = (const float4*)(x + (size_t)tok * DIM + k);
  float4 v0 = sp[0], v1 = sp[1];
  unsigned short t[8] = {f2bf(v0.x), f2bf(v0.y), f2bf(v0.z), f2bf(v0.w),
                         f2bf(v1.x), f2bf(v1.y), f2bf(v1.z), f2bf(v1.w)};
  *(uint4*)(Ab1 + ((size_t)sb * 32 + kblk) * 512 + lane * 8) = *(uint4*)t;
}

#define GEMM_BLOCKS 1024   // 4 blocks/CU x 256 CU (hard cap: 128 regs/wave, m69)

// XCD-bijective swizzle (T1): 1024 % 8 == 0 so the simple form is bijective.
__device__ __forceinline__ int xcd_swz(int bid) {
  return (bid & 7) * (GEMM_BLOCKS >> 3) + (bid >> 3);
}

// ---------------- GEMM1: He = gelu(Ab1 @ W1f + b1), He in frag order (Kd=2048) ----------------
// R12-exact form: direct u16 stores + erff (measured fastest: 112us).
__global__ __launch_bounds__(256, 4) void expert_gemm1(
    const unsigned short* __restrict__ Ab1,   // frag, Kd32=32
    const unsigned short* __restrict__ W1f,   // [E] frag, rows=HID, Kd32=32
    const float* __restrict__ b1,             // [E][H]
    const int* __restrict__ poffs,
    unsigned short* __restrict__ He) {        // frag, rows=CAPP, Kd32=64
  __shared__ __align__(16) unsigned short As[8192], Bs[8192];
  __shared__ int s_po[NE + 1];
  int tid = threadIdx.x, wid = tid >> 6, lane = tid & 63;
  if (tid <= NE) s_po[tid] = poffs[tid];
  __syncthreads();
  int nt = (s_po[NE] >> 7) << 4;              // row-tiles(128) x 16 col-tiles
  int m16 = lane & 15, q = lane >> 4;
  int wr = (wid & 1) << 6, wc = (wid >> 1) << 6;
  int ra = wr >> 4, rc = wc >> 4;
  unsigned short* lA = As + wid * 4 * 512;
  unsigned short* lB = Bs + wid * 4 * 512;
  f32x4_t zero4 = {0.f, 0.f, 0.f, 0.f};
  int bid0 = xcd_swz(blockIdx.x);

  for (int tile = bid0; tile < nt; tile += GEMM_BLOCKS) {
    int rt = tile >> 4, ct = tile & 15;
    int col0 = ct << 7;
    int row0 = rt << 7;                       // absolute slot row (region-aligned)
    int e = 0;
    while (e + 1 < NE && s_po[e + 1] <= row0) ++e;
    const unsigned short* Ag = Ab1 + ((size_t)((rt << 3) + wid * 2) * 32) * 512 + lane * 8;
    const unsigned short* Bg = W1f + (size_t)e * HID * DIM
                             + ((size_t)((col0 >> 4) + wid * 2) * 32) * 512 + lane * 8;
    f32x4_t acc[4][4];
    #pragma unroll
    for (int i = 0; i < 4; ++i)
      #pragma unroll
      for (int j = 0; j < 4; ++j) acc[i][j] = zero4;

    for (int k0 = 0; k0 < DIM; k0 += 64) {
      int kc = (k0 >> 5) * 512;
      load16_lds(Ag + kc,                  lA);
      load16_lds(Ag + kc + 512,            lA + 512);
      load16_lds(Ag + kc + 32 * 512,       lA + 1024);
      load16_lds(Ag + kc + 32 * 512 + 512, lA + 1536);
      load16_lds(Bg + kc,                  lB);
      load16_lds(Bg + kc + 512,            lB + 512);
      load16_lds(Bg + kc + 32 * 512,       lB + 1024);
      load16_lds(Bg + kc + 32 * 512 + 512, lB + 1536);
      __syncthreads();
      #pragma unroll
      for (int ks = 0; ks < 2; ++ks) {
        bf16x8_t a[4], b[4];
        #pragma unroll
        for (int i = 0; i < 4; ++i) {
          a[i] = *(const bf16x8_t*)&As[((ra + i) * 2 + ks) * 512 + lane * 8];
          b[i] = *(const bf16x8_t*)&Bs[((rc + i) * 2 + ks) * 512 + lane * 8];
        }
        #pragma unroll
        for (int i = 0; i < 4; ++i)
          #pragma unroll
          for (int j = 0; j < 4; ++j)
            acc[i][j] = __builtin_amdgcn_mfma_f32_16x16x32_bf16(a[i], b[j], acc[i][j], 0, 0, 0);
      }
      __syncthreads();
    }

    const float* b1e = b1 + (size_t)e * HID;
    int sb = rt << 3;
    #pragma unroll
    for (int i = 0; i < 4; ++i) {
      size_t sblk = (size_t)(sb + ra + i);
      #pragma unroll
      for (int rr = 0; rr < 4; ++rr) {
        int s15 = q * 4 + rr;   // slot & 15
        #pragma unroll
        for (int j = 0; j < 4; ++j) {
          int col = col0 + wc + j * 16 + m16;
          float v = acc[i][j][rr] + b1e[col];
          size_t off = (sblk * 64 + (col >> 5)) * 512 + (((col >> 3) & 3) * 16 + s15) * 8 + (col & 7);
          He[off] = f2bf(gelu_exact(v));
        }
      }
    }
  }
}

// ---------------- GEMM2: yb[slot] = He @ W2f (row-major out; bias+gate in LN) ----------------
__global__ __launch_bounds__(256, 4) void expert_gemm2(
    const unsigned short* __restrict__ He,    // frag, Kd32=64
    const unsigned short* __restrict__ W2f,   // [E] frag, rows=DIM, Kd32=64
    const int* __restrict__ poffs,
    unsigned short* __restrict__ yb) {        // [CAPP][DIM] row-major
  __shared__ __align__(16) unsigned short As[8192], Bs[8192];
  __shared__ int s_po[NE + 1];
  int tid = threadIdx.x, wid = tid >> 6, lane = tid & 63;
  if (tid <= NE) s_po[tid] = poffs[tid];
  __syncthreads();
  int nt = (s_po[NE] >> 7) << 3;              // row-tiles(128) x 8 col-tiles
  int m16 = lane & 15, q = lane >> 4;
  int wr = (wid & 1) << 6, wc = (wid >> 1) << 6;
  int ra = wr >> 4, rc = wc >> 4;
  unsigned short* lA = As + wid * 4 * 512;
  unsigned short* lB = Bs + wid * 4 * 512;
  f32x4_t zero4 = {0.f, 0.f, 0.f, 0.f};
  int bid0 = xcd_swz(blockIdx.x);

  for (int tile = bid0; tile < nt; tile += GEMM_BLOCKS) {
    int rt = tile >> 3, ct = tile & 7;
    int row0 = rt << 7;
    int col0 = ct << 7;
    int e = 0;
    while (e + 1 < NE && s_po[e + 1] <= row0) ++e;
    const unsigned short* Ag = He + ((size_t)((rt << 3) + wid * 2) * 64) * 512 + lane * 8;
    const unsigned short* Bg = W2f + (size_t)e * DIM * HID
                             + ((size_t)((col0 >> 4) + wid * 2) * 64) * 512 + lane * 8;
    f32x4_t acc[4][4];
    #pragma unroll
    for (int i = 0; i < 4; ++i)
      #pragma unroll
      for (int j = 0; j < 4; ++j) acc[i][j] = zero4;

    for (int k0 = 0; k0 < HID; k0 += 64) {
      int kc = (k0 >> 5) * 512;
      load16_lds(Ag + kc,                  lA);
      load16_lds(Ag + kc + 512,            lA + 512);
      load16_lds(Ag + kc + 64 * 512,       lA + 1024);
      load16_lds(Ag + kc + 64 * 512 + 512, lA + 1536);
      load16_lds(Bg + kc,                  lB);
      load16_lds(Bg + kc + 512,            lB + 512);
      load16_lds(Bg + kc + 64 * 512,       lB + 1024);
      load16_lds(Bg + kc + 64 * 512 + 512, lB + 1536);
      __syncthreads();
      #pragma unroll
      for (int ks = 0; ks < 2; ++ks) {
        bf16x8_t a[4], b[4];
        #pragma unroll
        for (int i = 0; i < 4; ++i) {
          a[i] = *(const bf16x8_t*)&As[((ra + i) * 2 + ks) * 512 + lane * 8];
          b[i] = *(const bf16x8_t*)&Bs[((rc + i) * 2 + ks) * 512 + lane * 8];
        }
        #pragma unroll
        for (int i = 0; i < 4; ++i)
          #pragma unroll
          for (int j = 0; j < 4; ++j)
            acc[i][j] = __builtin_amdgcn_mfma_f32_16x16x32_bf16(a[i], b[j], acc[i][j], 0, 0, 0);
      }
      __syncthreads();
    }

    #pragma unroll
    for (int i = 0; i < 4; ++i) {
      #pragma unroll
      for (int rr = 0; rr < 4; ++rr) {
        size_t slot = (size_t)(row0 + wr + i * 16 + q * 4 + rr);
        #pragma unroll
        for (int j = 0; j < 4; ++j) {
          int col = col0 + wc + j * 16 + m16;
          yb[slot * DIM + col] = f2bf(acc[i][j][rr]);
        }
      }
    }
  }
}

// ---------------- gather + gate + bias + residual + LayerNorm (vectorized) ----------------
__global__ __launch_bounds__(256) void ln_kernel(
    const float* __restrict__ x, const unsigned short* __restrict__ yb,
    const int* __restrict__ tok_e, const float* __restrict__ tok_g,
    const int* __restrict__ pair_slot, const float* __restrict__ b2,
    const float* __restrict__ gamma, const float* __restrict__ beta,
    float* __restrict__ out) {
  int n = blockIdx.x, tid = threadIdx.x;
  int e0 = tok_e[2 * n], e1 = tok_e[2 * n + 1];
  float g0 = tok_g[2 * n], g1 = tok_g[2 * n + 1];
  size_t s0 = (size_t)pair_slot[2 * n], s1 = (size_t)pair_slot[2 * n + 1];
  const float* xr = x + (size_t)n * DIM;
  const unsigned short* y0 = yb + s0 * DIM;
  const unsigned short* y1 = yb + s1 * DIM;
  const float* b2e0 = b2 + (size_t)e0 * DIM;
  const float* b2e1 = b2 + (size_t)e1 * DIM;
  int d0 = tid << 2;   // thread owns elements d0..d0+3 (256*4 = 1024)
  float4 xv  = *(const float4*)(xr + d0);
  ushort4 yv0 = *(const ushort4*)(y0 + d0);
  ushort4 yv1 = *(const ushort4*)(y1 + d0);
  float4 bv0 = *(const float4*)(b2e0 + d0);
  float4 bv1 = *(const float4*)(b2e1 + d0);
  float z[4], s = 0.f, s2 = 0.f;
  {
    const float* xp = (const float*)&xv;
    const unsigned short* y0p = (const unsigned short*)&yv0;
    const unsigned short* y1p = (const unsigned short*)&yv1;
    const float* b0p = (const float*)&bv0;
    const float* b1p = (const float*)&bv1;
    #pragma unroll
    for (int jj = 0; jj < 4; ++jj) {
      float v = xp[jj] + g0 * (bf2f(y0p[jj]) + b0p[jj]) + g1 * (bf2f(y1p[jj]) + b1p[jj]);
      z[jj] = v; s += v; s2 += v * v;
    }
  }
  for (int o = 32; o > 0; o >>= 1) { s += __shfl_down(s, o, 64); s2 += __shfl_down(s2, o, 64); }
  __shared__ float rs[4], rs2[4];
  int wid = tid >> 6, lane = tid & 63;
  if (lane == 0) { rs[wid] = s; rs2[wid] = s2; }
  __syncthreads();
  float ts = rs[0] + rs[1] + rs[2] + rs[3];
  float ts2 = rs2[0] + rs2[1] + rs2[2] + rs2[3];
  float mu = ts * (1.f / DIM);
  float var = ts2 * (1.f / DIM) - mu * mu;
  float rstd = rsqrtf(var + 1e-5f);
  float4 gv = *(const float4*)(gamma + d0);
  float4 bv = *(const float4*)(beta + d0);
  float4 ov;
  {
    const float* gp = (const float*)&gv;
    const float* bp = (const float*)&bv;
    float* op = (float*)&ov;
    #pragma unroll
    for (int jj = 0; jj < 4; ++jj)
      op[jj] = (z[jj] - mu) * rstd * gp[jj] + bp[jj];
  }
  *(float4*)(out + (size_t)n * DIM + d0) = ov;
}

extern "C" void kernel_launch(void* const* d_in, const int* in_sizes, int n_in,
                              void* d_out, int out_size, void* d_ws, size_t ws_size,
                              hipStream_t stream) {
  const float* x     = (const float*)d_in[0];
  const float* gW    = (const float*)d_in[1];
  const float* gb    = (const float*)d_in[2];
  const float* W1    = (const float*)d_in[3];
  const float* b1    = (const float*)d_in[4];
  const float* W2    = (const float*)d_in[5];
  const float* b2    = (const float*)d_in[6];
  const float* gamma = (const float*)d_in[7];
  const float* beta  = (const float*)d_in[8];
  float* out = (float*)d_out;

  // workspace layout (~166 MB), all chunks 16B-aligned
  char* w = (char*)d_ws;
  unsigned short* W1f = (unsigned short*)w; w += (size_t)NE * HID * DIM * 2;
  unsigned short* W2f = (unsigned short*)w; w += (size_t)NE * DIM * HID * 2;
  unsigned short* He  = (unsigned short*)w; w += (size_t)CAPP * HID * 2;
  unsigned short* AbY = (unsigned short*)w; w += (size_t)CAPP * DIM * 2;  // Ab1, then yb (aliased)
  int*   row_token    = (int*)w;            w += (size_t)CAPP * 4;
  float* row_gate     = (float*)w;          w += (size_t)CAPP * 4;
  int*   tok_e        = (int*)w;            w += (size_t)NPAIR * 4;
  float* tok_g        = (float*)w;          w += (size_t)NPAIR * 4;
  int*   pair_slot    = (int*)w;            w += (size_t)NPAIR * 4;
  float* imp          = (float*)w;          // stats region (256B, zeroed by w_to_frag_all):
  float* ent_sum      = imp + 8;            //   imp[8], ent_sum[1]+pad
  int*   cntp         = (int*)(imp + 16);   //   cnt[8]
  int*   cursor       = cntp + 8;           //   cursor[8] (zero-based)
  int*   poffs        = cursor + 8;         //   poffs[9] (written by scatter blk0)

  unsigned short* Ab1 = AbY;                // gemm1 input (dead after gemm1)
  unsigned short* yb  = AbY;                // gemm2 output (written after Ab1 dead)

  // 7 enqueues (was 10): memset + finalize removed, w_to_frag pair merged.
  w_to_frag_all<<<4096, 256, 0, stream>>>(W1, W2, W1f, W2f, imp);
  router_kernel<<<R_BLOCKS, 256, 0, stream>>>(x, gW, gb, tok_e, tok_g, cntp, imp, ent_sum);
  scatter_kernel<<<N_TOK / 256, 256, 0, stream>>>(tok_e, tok_g, cntp, imp, ent_sum,
                                                  cursor, poffs, out + TAIL,
                                                  row_token, row_gate, pair_slot);
  gather_a1<<<GA_BLOCKS, 256, 0, stream>>>(x, row_token, cntp, poffs, Ab1);
  expert_gemm1<<<GEMM_BLOCKS, 256, 0, stream>>>(Ab1, W1f, b1, poffs, He);
  expert_gemm2<<<GEMM_BLOCKS, 256, 0, stream>>>(He, W2f, poffs, yb);
  ln_kernel<<<N_TOK, 256, 0, stream>>>(x, yb, tok_e, tok_g, pair_slot, b2, gamma, beta, out);
}